// Round 2
// baseline (306.426 us; speedup 1.0000x reference)
//
#include <hip/hip_runtime.h>
#include <hip/hip_bf16.h>
#include <math.h>

#define BB 32
#define SS 512
#define EE 300
#define FF 100
#define TT 50
#define CH 16            // steps per chunk-product
#define NC 32            // chunks = 512/16

typedef __attribute__((ext_vector_type(8))) short v8s;   // 8 bf16
typedef __attribute__((ext_vector_type(4))) float v4f;   // 4 f32
#define MFMA16 __builtin_amdgcn_mfma_f32_16x16x32_bf16

#define AP 328           // emb LDS stride (shorts): 164 words -> 2-way max (free)
#define NCH 10           // conv K-chunks of 96
#define CKS 3            // k-steps per chunk
#define CHB (128 * 96)   // shorts per conv B chunk buffer (24576 B)
#define A2P 136          // feat LDS stride (shorts): 68 words -> 2-way (free)
#define MP 72            // tree-product LDS row stride (shorts; 144 B, 16B-aligned rows)

__device__ inline unsigned short f2bf(float v) {
    unsigned u = __float_as_uint(v);
    unsigned r = u + 0x7fff + ((u >> 16) & 1);
    return (unsigned short)(r >> 16);
}
__device__ inline float bf2f(short s) {
    return __uint_as_float(((unsigned)(unsigned short)s) << 16);
}
__device__ inline unsigned pkbf2(float a, float b) {   // v_cvt_pk_bf16_f32
    __hip_bfloat162 h = __float22bfloat162_rn(make_float2(a, b));
    return *(unsigned*)&h;
}
__device__ inline v8s ldsld8(const short* p) {
    return *(const v8s*)__builtin_assume_aligned(p, 16);
}
__device__ inline void g2lds16(const void* g, void* l) {
    __builtin_amdgcn_global_load_lds(
        (const __attribute__((address_space(1))) unsigned int*)g,
        (__attribute__((address_space(3))) unsigned int*)l, 16, 0, 0);
}

// ---------------------------------------------------------------------------
// Kernel 0: fragment-linear bf16 weight layouts + bf16 exp(trans) matrices
// + zero the atomic accumulators/counters (workspace is re-poisoned per iter).
// ---------------------------------------------------------------------------
__global__ void prep_kernel(const float* __restrict__ tr, const float* __restrict__ cw,
                            const float* __restrict__ fcw,
                            unsigned short* __restrict__ wB2,
                            unsigned short* __restrict__ fcwT2,
                            unsigned short* __restrict__ AT,
                            unsigned short* __restrict__ Ab,
                            float* __restrict__ accum, unsigned* __restrict__ cnt,
                            float* __restrict__ nllpart, unsigned* __restrict__ doneb)
{
    const int gid = blockIdx.x * 256 + threadIdx.x;
    const int gs  = 64 * 256;
    if (gid == 0) { *accum = 0.f; *cnt = 0u; }
    if (gid < BB) { nllpart[gid] = 0.f; doneb[gid] = 0u; }
    for (int idx = gid; idx < NCH * CKS * 8 * 512; idx += gs) {
        int e = idx & 7, p = (idx >> 3) & 63, blk = idx >> 9;
        int ch = blk / 24, rem = blk - ch * 24;
        int sl = rem >> 3, ft = rem & 7;
        int col = p >> 2, q = p & 3;
        int n  = ft * 16 + col;
        int gk = ch * 96 + sl * 32 + q * 8 + e;
        int kk = gk / 320, ee = gk - kk * 320;
        float v = (n < FF && ee < EE) ? cw[n * 900 + ee * 3 + kk] : 0.f;
        wB2[idx] = f2bf(v);
    }
    for (int idx = gid; idx < 16 * 512; idx += gs) {
        int e = idx & 7, p = (idx >> 3) & 63, blk = idx >> 9;
        int ks = blk >> 2, nt = blk & 3;
        int col = p >> 2, q = p & 3;
        int t = nt * 16 + col, f = ks * 32 + q * 8 + e;
        float v = (t < TT && f < FF) ? fcw[t * FF + f] : 0.f;
        fcwT2[idx] = f2bf(v);
    }
    for (int idx = gid; idx < 64 * 64; idx += gs) {
        int r = idx >> 6, c2 = idx & 63;
        AT[idx] = (r < TT && c2 < TT) ? f2bf(__expf(tr[c2 * TT + r])) : 0;
        Ab[idx] = (r < TT && c2 < TT) ? f2bf(__expf(tr[r * TT + c2])) : 0;
    }
}

// ---------------------------------------------------------------------------
// Kernel A: MFMA conv(K=3) + FC, with CRF numerator folded into the epilogue.
// grid (16, 32), 256 threads (4 waves). (unchanged from round 1 -- passed)
// ---------------------------------------------------------------------------
__global__ __launch_bounds__(256, 3) void emis_kernel(
    const int* __restrict__ x, const float* __restrict__ emb,
    const unsigned short* __restrict__ wB2, const float* __restrict__ cb,
    const unsigned short* __restrict__ fcwT2, const float* __restrict__ fcb,
    const int* __restrict__ tags, const float* __restrict__ tr,
    const float* __restrict__ start, const float* __restrict__ endt,
    float* __restrict__ expem, float* __restrict__ nllpart)
{
    __shared__ __align__(16) short ldsA[34 * AP];       // 22304 B (reused as feat)
    __shared__ __align__(16) short ldsB[CHB];           // 24576 B (weights)
    __shared__ float redN[2];

    const int b    = blockIdx.y;
    const int s0   = blockIdx.x * 32;
    const int tid  = threadIdx.x;
    const int wv   = tid >> 6;
    const int lane = tid & 63;
    const int col  = lane & 15;
    const int q    = lane >> 4;
    const int bofs = ((col << 2) | q) << 3;             // fragment-linear lane offset

#pragma unroll
    for (int it = 0; it < 6; ++it) {
        int seg = it * 4 + wv;
        g2lds16((const char*)wB2 + seg * 1024 + lane * 16,
                (char*)ldsB + seg * 1024);
    }

    int   xr[10], ofs[10], e0a[10];
#pragma unroll
    for (int it = 0; it < 10; ++it) {
        int g = tid + it * 256;
        int r = g / 75, eg = g - r * 75;
        int e0 = eg * 4;
        int src = s0 - 1 + r;
        bool v = (g < 2550) && (src >= 0) && (src < SS);
        xr[it]  = v ? x[b * SS + src] : -1;
        ofs[it] = r * AP + e0;
        e0a[it] = e0;
    }
    float4 vv[10];
#pragma unroll
    for (int it = 0; it < 10; ++it)
        vv[it] = (xr[it] >= 0)
               ? *(const float4*)(emb + (size_t)xr[it] * EE + e0a[it])
               : make_float4(0.f, 0.f, 0.f, 0.f);
#pragma unroll
    for (int it = 0; it < 10; ++it) {
        int g = tid + it * 256;
        if (g < 2550) {
            unsigned lo = pkbf2(vv[it].x, vv[it].y);
            unsigned hi = pkbf2(vv[it].z, vv[it].w);
            *(uint2*)&ldsA[ofs[it]] = make_uint2(lo, hi);
        }
    }
    if (tid < 34 * 5) {
        int r = tid / 5, c0 = 300 + (tid % 5) * 4;
        *(short4*)&ldsA[r * AP + c0] = make_short4(0, 0, 0, 0);
    }

    v4f acc[2][2];
#pragma unroll
    for (int a = 0; a < 2; ++a)
#pragma unroll
        for (int f = 0; f < 2; ++f) acc[a][f] = (v4f){0.f, 0.f, 0.f, 0.f};

    const int ftA = wv * 2, ftB = wv * 2 + 1;
    for (int ch = 0; ch < NCH; ++ch) {
        __syncthreads();
#pragma unroll
        for (int sl = 0; sl < CKS; ++sl) {
            int gk = ch * 96 + sl * 32;
            int kk = (gk >= 640) ? 2 : (gk >= 320 ? 1 : 0);
            int e0 = gk - kk * 320;
            v8s a0 = ldsld8(&ldsA[(col + kk) * AP + e0 + q * 8]);
            v8s a1 = ldsld8(&ldsA[(16 + col + kk) * AP + e0 + q * 8]);
            v8s b0 = ldsld8(&ldsB[((sl * 8 + ftA) << 9) + bofs]);
            v8s b1 = ldsld8(&ldsB[((sl * 8 + ftB) << 9) + bofs]);
            acc[0][0] = MFMA16(a0, b0, acc[0][0], 0, 0, 0);
            acc[0][1] = MFMA16(a0, b1, acc[0][1], 0, 0, 0);
            acc[1][0] = MFMA16(a1, b0, acc[1][0], 0, 0, 0);
            acc[1][1] = MFMA16(a1, b1, acc[1][1], 0, 0, 0);
        }
        __syncthreads();
        if (ch < NCH - 1) {
            const char* g = (const char*)(wB2 + (size_t)(ch + 1) * CHB);
#pragma unroll
            for (int it = 0; it < 6; ++it) {
                int seg = it * 4 + wv;
                g2lds16(g + seg * 1024 + lane * 16, (char*)ldsB + seg * 1024);
            }
        }
    }

    short* A2 = ldsA;
    short* B2 = ldsB;
#pragma unroll
    for (int it = 0; it < 4; ++it) {
        int seg = it * 4 + wv;
        g2lds16((const char*)fcwT2 + seg * 1024 + lane * 16,
                (char*)B2 + seg * 1024);
    }
#pragma unroll
    for (int st = 0; st < 2; ++st)
#pragma unroll
        for (int fi = 0; fi < 2; ++fi) {
            int f = (wv * 2 + fi) * 16 + col;
            float bias = (f < FF) ? cb[f] : 0.f;
#pragma unroll
            for (int rg = 0; rg < 4; ++rg) {
                int s = st * 16 + q * 4 + rg;
                float v = (f < FF) ? fmaxf(acc[st][fi][rg] + bias, 0.f) : 0.f;
                A2[s * A2P + f] = (short)f2bf(v);
            }
        }
    __syncthreads();

    if (wv < 2) {
        v4f a2[4];
#pragma unroll
        for (int nt = 0; nt < 4; ++nt) a2[nt] = (v4f){0.f, 0.f, 0.f, 0.f};
#pragma unroll
        for (int ks = 0; ks < 4; ++ks) {
            v8s af = ldsld8(&A2[(wv * 16 + col) * A2P + ks * 32 + q * 8]);
#pragma unroll
            for (int nt = 0; nt < 4; ++nt) {
                v8s bt = ldsld8(&B2[((ks * 4 + nt) << 9) + bofs]);
                a2[nt] = MFMA16(af, bt, a2[nt], 0, 0, 0);
            }
        }
        float fb0 = fcb[col], fb1 = fcb[16 + col], fb2 = fcb[32 + col];
        float fb3 = (col < 2) ? fcb[48 + col] : 0.f;
        float nllp = 0.f;
#pragma unroll
        for (int rg = 0; rg < 4; ++rg) {
            int s = s0 + wv * 16 + q * 4 + rg;
            float e0v = a2[0][rg] + fb0;
            float e1v = a2[1][rg] + fb1;
            float e2v = a2[2][rg] + fb2;
            float e3v = (col < 2) ? a2[3][rg] + fb3 : -1e30f;
            float m = fmaxf(fmaxf(e0v, e1v), fmaxf(e2v, e3v));
#pragma unroll
            for (int off = 1; off < 16; off <<= 1) m = fmaxf(m, __shfl_xor(m, off));
            int gidx = b * SS + s;
            int tg = tags[gidx];
            float* orow = expem + (size_t)gidx * TT;
            orow[col]      = __expf(e0v - m);
            orow[16 + col] = __expf(e1v - m);
            orow[32 + col] = __expf(e2v - m);
            if (col < 2) orow[48 + col] = __expf(e3v - m);
            if (tg == col)            nllp -= e0v;
            else if (tg == 16 + col)  nllp -= e1v;
            else if (tg == 32 + col)  nllp -= e2v;
            else if (col < 2 && tg == 48 + col) nllp -= e3v;
            if (col == 0) {
                nllp += m;
                if (s < SS - 1) nllp -= tr[tg * TT + tags[gidx + 1]];
                if (s == 0)      nllp -= start[tg];
                if (s == SS - 1) nllp -= endt[tg];
            }
        }
#pragma unroll
        for (int off = 1; off < 64; off <<= 1) nllp += __shfl_xor(nllp, off);
        if (lane == 0) redN[wv] = nllp;
    }
    __syncthreads();
    if (tid == 0) atomicAdd(nllpart + b, redN[0] + redN[1]);
}

// ---------------------------------------------------------------------------
// Tree-product helpers. All matrices 64x64 bf16 in LDS with row stride MP.
// "T-form"  : S[n][k] = Mat[k][n]  (B-operand layout, vectorized stores)
// "RM-form" : S[m][k] = Mat[m][k]  (A-operand layout, scalar stores)
// Both are READ with the identical fragment address pattern.
// ---------------------------------------------------------------------------
__device__ inline v8s idfrag(int row, int kbase) {     // identity-matrix fragment
    v8s r;
#pragma unroll
    for (int e = 0; e < 8; ++e) r[e] = (short)((kbase + e == row) ? 0x3F80 : 0);
    return r;
}

__device__ inline void prodLDS(const short* SA, const short* SB, int col, int q,
                               v4f (&acc)[4][4]) {
    v8s a[4][2], bb[4][2];
#pragma unroll
    for (int jt = 0; jt < 4; ++jt)
#pragma unroll
        for (int kc = 0; kc < 2; ++kc)
            a[jt][kc] = ldsld8(&SA[(jt * 16 + col) * MP + kc * 32 + q * 8]);
#pragma unroll
    for (int nt = 0; nt < 4; ++nt)
#pragma unroll
        for (int kc = 0; kc < 2; ++kc)
            bb[nt][kc] = ldsld8(&SB[(nt * 16 + col) * MP + kc * 32 + q * 8]);
#pragma unroll
    for (int jt = 0; jt < 4; ++jt)
#pragma unroll
        for (int nt = 0; nt < 4; ++nt) {
            acc[jt][nt] = (v4f){0.f, 0.f, 0.f, 0.f};
            acc[jt][nt] = MFMA16(a[jt][0], bb[nt][0], acc[jt][nt], 0, 0, 0);
            acc[jt][nt] = MFMA16(a[jt][1], bb[nt][1], acc[jt][nt], 0, 0, 0);
        }
}

__device__ inline void storeT(short* SD, int col, int q, const v4f (&acc)[4][4]) {
#pragma unroll
    for (int jt = 0; jt < 4; ++jt)
#pragma unroll
        for (int nt = 0; nt < 4; ++nt) {
            uint2 o = make_uint2(pkbf2(acc[jt][nt][0], acc[jt][nt][1]),
                                 pkbf2(acc[jt][nt][2], acc[jt][nt][3]));
            *(uint2*)&SD[(nt * 16 + col) * MP + jt * 16 + q * 4] = o;
        }
}

__device__ inline void storeRM(short* SD, int col, int q, const v4f (&acc)[4][4]) {
#pragma unroll
    for (int jt = 0; jt < 4; ++jt)
#pragma unroll
        for (int nt = 0; nt < 4; ++nt)
#pragma unroll
            for (int r = 0; r < 4; ++r)
                SD[(jt * 16 + q * 4 + r) * MP + nt * 16 + col] =
                    (short)f2bf(acc[jt][nt][r]);
}

// ---------------------------------------------------------------------------
// Kernel B (tree + fused chain): per-(batch,chunk) product of 16 step
// matrices M_t = diag(em_t)*A^T via a pairwise TREE (depth 4, not 15):
//   level 1 (8 waves): N_w = M_{2w+1}*M_{2w}   -- leaves synthesized from
//       L2-hot AT/Ab, em row-scaling folded into the store epilogue
//       (D*(A^T*Y) = (D*A^T)*Y), so no sequential dependence at all.
//   level 2 (4 waves), level 3 (2 waves), level 4 (wave 0) from LDS.
// Same FLOPs as the sequential scan, 4 bf16 roundings instead of 15.
// Last chunk block per batch runs the vector chain (round-1 protocol, passed).
// grid (NC, BB), 512 threads (8 waves).
// ---------------------------------------------------------------------------
__global__ __launch_bounds__(512) void chunkchain_kernel(
    const float* __restrict__ expem, const unsigned short* __restrict__ AT,
    const unsigned short* __restrict__ Ab,
    unsigned short* __restrict__ R, float* __restrict__ lsR,
    const float* __restrict__ start, const float* __restrict__ endt,
    const float* __restrict__ nllpart, unsigned* __restrict__ doneb,
    float* __restrict__ accum, unsigned* __restrict__ cnt,
    float* __restrict__ out)
{
    __shared__ __align__(16) short S[8][64 * MP];   // 73728 B product slots
    __shared__ __align__(16) float emL[CH][64];     // 4096 B
    __shared__ unsigned lastf;
    const int c = blockIdx.x, b = blockIdx.y;
    const int tid  = threadIdx.x;
    const int wv   = tid >> 6;
    const int lane = tid & 63;
    const int col = lane & 15, q = lane >> 4;
    const int t0 = c * CH + 1;
    const int nf = (c == NC - 1) ? (SS - 1 - (NC - 1) * CH) : CH;   // 15 or 16

    for (int idx = tid; idx < CH * 64; idx += 512) {
        int k = idx >> 6, m = idx & 63;
        float v = 0.f;
        if (m < TT && k < nf) v = expem[((size_t)(b * SS + t0 + k)) * TT + m];
        emL[k][m] = v;
    }
    __syncthreads();

    // ---- level 1: wave w computes N_w = M_{2w+1} * M_{2w} ----
    {
        const int tX = 2 * wv + 1, tY = 2 * wv;
        const bool idX = (tX >= nf), idY = (tY >= nf);
        v4f acc[4][4];
        {
            v8s af[4][2];
#pragma unroll
            for (int jt = 0; jt < 4; ++jt)
#pragma unroll
                for (int kc = 0; kc < 2; ++kc)
                    af[jt][kc] = idX
                        ? idfrag(jt * 16 + col, kc * 32 + q * 8)
                        : *(const v8s*)(AT + (jt * 16 + col) * 64 + kc * 32 + q * 8);
#pragma unroll
            for (int jt = 0; jt < 4; ++jt)
#pragma unroll
                for (int nt = 0; nt < 4; ++nt) acc[jt][nt] = (v4f){0.f, 0.f, 0.f, 0.f};
#pragma unroll
            for (int kc = 0; kc < 2; ++kc) {
                const int kb = kc * 32 + q * 8;
                float4 eA = *(const float4*)&emL[tY][kb];
                float4 eB = *(const float4*)&emL[tY][kb + 4];
#pragma unroll
                for (int nt = 0; nt < 4; ++nt) {
                    v8s bfr;
                    if (idY) bfr = idfrag(nt * 16 + col, kb);
                    else {
                        v8s ab = *(const v8s*)(Ab + (nt * 16 + col) * 64 + kb);
                        unsigned u0 = pkbf2(bf2f(ab[0]) * eA.x, bf2f(ab[1]) * eA.y);
                        unsigned u1 = pkbf2(bf2f(ab[2]) * eA.z, bf2f(ab[3]) * eA.w);
                        unsigned u2 = pkbf2(bf2f(ab[4]) * eB.x, bf2f(ab[5]) * eB.y);
                        unsigned u3 = pkbf2(bf2f(ab[6]) * eB.z, bf2f(ab[7]) * eB.w);
                        ((unsigned*)&bfr)[0] = u0; ((unsigned*)&bfr)[1] = u1;
                        ((unsigned*)&bfr)[2] = u2; ((unsigned*)&bfr)[3] = u3;
                    }
#pragma unroll
                    for (int jt = 0; jt < 4; ++jt)
                        acc[jt][nt] = MFMA16(af[jt][kc], bfr, acc[jt][nt], 0, 0, 0);
                }
            }
        }
        // epilogue: row-scale by em_{tX} (folded D), store N_w into slot wv
        if (wv & 1) {   // A-operand at level 2 -> RM-form
#pragma unroll
            for (int jt = 0; jt < 4; ++jt) {
                float4 e4 = idX ? make_float4(1.f, 1.f, 1.f, 1.f)
                                : *(const float4*)&emL[tX][jt * 16 + q * 4];
#pragma unroll
                for (int nt = 0; nt < 4; ++nt) {
                    S[wv][(jt * 16 + q * 4 + 0) * MP + nt * 16 + col] = (short)f2bf(acc[jt][nt][0] * e4.x);
                    S[wv][(jt * 16 + q * 4 + 1) * MP + nt * 16 + col] = (short)f2bf(acc[jt][nt][1] * e4.y);
                    S[wv][(jt * 16 + q * 4 + 2) * MP + nt * 16 + col] = (short)f2bf(acc[jt][nt][2] * e4.z);
                    S[wv][(jt * 16 + q * 4 + 3) * MP + nt * 16 + col] = (short)f2bf(acc[jt][nt][3] * e4.w);
                }
            }
        } else {        // B-operand at level 2 -> T-form
#pragma unroll
            for (int jt = 0; jt < 4; ++jt) {
                float4 e4 = idX ? make_float4(1.f, 1.f, 1.f, 1.f)
                                : *(const float4*)&emL[tX][jt * 16 + q * 4];
#pragma unroll
                for (int nt = 0; nt < 4; ++nt) {
                    uint2 o = make_uint2(
                        pkbf2(acc[jt][nt][0] * e4.x, acc[jt][nt][1] * e4.y),
                        pkbf2(acc[jt][nt][2] * e4.z, acc[jt][nt][3] * e4.w));
                    *(uint2*)&S[wv][(nt * 16 + col) * MP + jt * 16 + q * 4] = o;
                }
            }
        }
    }
    __syncthreads();

    // ---- level 2: wave j<4: Q_j = N_{2j+1} * N_{2j} -> slot 2j ----
    if (wv < 4) {
        v4f acc[4][4];
        prodLDS(S[2 * wv + 1], S[2 * wv], col, q, acc);
        if (wv & 1) storeRM(S[2 * wv], col, q, acc);
        else        storeT (S[2 * wv], col, q, acc);
    }
    __syncthreads();

    // ---- level 3: wave i<2: R_i = Q_{2i+1} * Q_{2i} -> slot 4i ----
    if (wv < 2) {
        v4f acc[4][4];
        prodLDS(S[4 * wv + 2], S[4 * wv], col, q, acc);
        if (wv) storeRM(S[4], col, q, acc);
        else    storeT (S[0], col, q, acc);
    }
    __syncthreads();

    // ---- level 4 (wave 0): P = R_1 * R_0; rescale by max; write R, lsR ----
    if (wv == 0) {
        v4f acc[4][4];
        prodLDS(S[4], S[0], col, q, acc);
        float mx = 0.f;
#pragma unroll
        for (int jt = 0; jt < 4; ++jt)
#pragma unroll
            for (int nt = 0; nt < 4; ++nt)
#pragma unroll
                for (int r = 0; r < 4; ++r) mx = fmaxf(mx, acc[jt][nt][r]);
#pragma unroll
        for (int off = 1; off < 64; off <<= 1) mx = fmaxf(mx, __shfl_xor(mx, off));
        mx = fmaxf(mx, 1e-37f);
        float inv = 1.f / mx;
        unsigned short* Rc = R + ((size_t)(b * NC + c) << 12);
#pragma unroll
        for (int jt = 0; jt < 4; ++jt)
#pragma unroll
            for (int nt = 0; nt < 4; ++nt)
#pragma unroll
                for (int r = 0; r < 4; ++r)
                    Rc[(jt * 16 + q * 4 + r) * 64 + nt * 16 + col] =
                        f2bf(acc[jt][nt][r] * inv);
        if (tid == 0) lsR[b * NC + c] = __logf(mx);
    }

    // ---- completion protocol: last chunk block of batch b runs the chain ----
    if (tid == 0) {
        __threadfence();                       // release our R/lsR writes
        unsigned o = atomicAdd(doneb + b, 1u);
        lastf = (o == NC - 1) ? 1u : 0u;
    }
    __syncthreads();
    if (!lastf || wv != 0) return;

    __threadfence();                           // acquire
    const int i = lane;
    float* pvec = &emL[0][0];                  // reuse dead LDS
    pvec[i] = (i < TT) ? __expf(start[i]) * expem[((size_t)(b * SS)) * TT + i] : 0.f;
    const unsigned short* Rb = R + ((size_t)(b * NC) << 12);
    v8s rb[4][8];                              // prefetch depth 4
#pragma unroll
    for (int pc = 0; pc < 4; ++pc)
#pragma unroll
        for (int g = 0; g < 8; ++g)
            rb[pc][g] = *(const v8s*)(Rb + ((size_t)pc << 12) + i * 64 + g * 8);
    float logacc = 0.f;
#pragma unroll
    for (int cc = 0; cc < NC; ++cc) {
        const int slot = cc & 3;
        const float4* pv4 = (const float4*)pvec;
        float a0 = 0.f, a1 = 0.f, a2 = 0.f, a3 = 0.f;   // 4 chains
#pragma unroll
        for (int g = 0; g < 8; ++g) {
            v8s v = rb[slot][g];
            float4 pA = pv4[g * 2], pB = pv4[g * 2 + 1];
            float* aa = (g & 3) == 0 ? &a0 : (g & 3) == 1 ? &a1 : (g & 3) == 2 ? &a2 : &a3;
            float t = *aa;
            t = fmaf(bf2f(v[0]), pA.x, t);
            t = fmaf(bf2f(v[1]), pA.y, t);
            t = fmaf(bf2f(v[2]), pA.z, t);
            t = fmaf(bf2f(v[3]), pA.w, t);
            t = fmaf(bf2f(v[4]), pB.x, t);
            t = fmaf(bf2f(v[5]), pB.y, t);
            t = fmaf(bf2f(v[6]), pB.z, t);
            t = fmaf(bf2f(v[7]), pB.w, t);
            *aa = t;
        }
        float acc2 = (a0 + a1) + (a2 + a3);
        if (cc + 4 < NC) {
            const unsigned short* Rn = Rb + ((size_t)(cc + 4) << 12);
#pragma unroll
            for (int g = 0; g < 8; ++g)
                rb[slot][g] = *(const v8s*)(Rn + i * 64 + g * 8);
        }
        float mx = acc2;
#pragma unroll
        for (int off = 1; off < 64; off <<= 1) mx = fmaxf(mx, __shfl_xor(mx, off));
        mx = fmaxf(mx, 1e-37f);
        logacc += __logf(mx) + lsR[b * NC + cc];
        pvec[i] = acc2 * (1.f / mx);
    }
    float sv = (i < TT) ? pvec[i] * __expf(endt[i]) : 0.f;
#pragma unroll
    for (int off = 1; off < 64; off <<= 1) sv += __shfl_xor(sv, off);
    if (i == 0) {
        float nll = nllpart[b] + logacc + __logf(sv);
        atomicAdd(accum, nll);
        __threadfence();
        unsigned o = atomicAdd(cnt, 1u);
        if (o == BB - 1) out[0] = atomicAdd(accum, 0.f);
    }
}

extern "C" void kernel_launch(void* const* d_in, const int* in_sizes, int n_in,
                              void* d_out, int out_size, void* d_ws, size_t ws_size,
                              hipStream_t stream)
{
    const int*   x    = (const int*)d_in[0];
    const int*   tags = (const int*)d_in[1];
    const float* emb  = (const float*)d_in[2];
    const float* cw   = (const float*)d_in[3];
    const float* cb   = (const float*)d_in[4];
    const float* fcw  = (const float*)d_in[5];
    const float* fcb  = (const float*)d_in[6];
    const float* st   = (const float*)d_in[7];
    const float* en   = (const float*)d_in[8];
    const float* tr   = (const float*)d_in[9];

    unsigned short* wB2   = (unsigned short*)d_ws;            // 122880 sh
    unsigned short* fcwT2 = wB2 + NCH * CKS * 8 * 512;        // 8192 sh
    unsigned short* ATm   = fcwT2 + 16 * 512;                 // 4096 sh
    unsigned short* Abm   = ATm + 4096;                       // 4096 sh
    unsigned short* Rm    = Abm + 4096;                       // BB*NC*4096 sh = 8 MB
    float* fbase   = (float*)(Rm + (size_t)BB * NC * 4096);
    float* expem   = fbase;                                   // 819200
    float* lsR     = expem + (size_t)BB * SS * TT;            // 1024
    float* nllpart = lsR + BB * NC;                           // 32
    float* accum   = nllpart + BB;                            // 1
    unsigned* cnt  = (unsigned*)(accum + 1);                  // 1
    unsigned* doneb = cnt + 1;                                // 32

    prep_kernel<<<dim3(64), 256, 0, stream>>>(tr, cw, fcw, wB2, fcwT2, ATm, Abm,
                                              accum, cnt, nllpart, doneb);
    emis_kernel<<<dim3(16, BB), 256, 0, stream>>>(x, emb, wB2, cb, fcwT2, fcb,
                                                  tags, tr, st, en, expem, nllpart);
    chunkchain_kernel<<<dim3(NC, BB), 512, 0, stream>>>(expem, ATm, Abm, Rm, lsR,
                                                        st, en, nllpart, doneb,
                                                        accum, cnt, (float*)d_out);
}

// Round 3
// 287.040 us; speedup vs baseline: 1.0675x; 1.0675x over previous
//
#include <hip/hip_runtime.h>
#include <hip/hip_bf16.h>
#include <math.h>

#define BB 32
#define SS 512
#define EE 300
#define FF 100
#define TT 50
#define CH 16            // steps per chunk-product (15 multiplies, overflow-safe)
#define NC 32            // chunks = 512/16

typedef __attribute__((ext_vector_type(8))) short v8s;   // 8 bf16
typedef __attribute__((ext_vector_type(4))) float v4f;   // 4 f32
#define MFMA16 __builtin_amdgcn_mfma_f32_16x16x32_bf16

#define AP 328           // emb LDS stride (shorts): 164 words -> 2-way max (free)
#define NCH 10           // conv K-chunks of 96
#define CKS 3            // k-steps per chunk
#define CHB (128 * 96)   // shorts per conv B chunk buffer (24576 B)
#define A2P 136          // feat LDS stride (shorts): 68 words -> 2-way (free)
#define MP 72            // chunk-product LDS row stride (bf16)

__device__ inline unsigned short f2bf(float v) {
    unsigned u = __float_as_uint(v);
    unsigned r = u + 0x7fff + ((u >> 16) & 1);
    return (unsigned short)(r >> 16);
}
__device__ inline float bf2f(short s) {
    return __uint_as_float(((unsigned)(unsigned short)s) << 16);
}
__device__ inline unsigned pkbf2(float a, float b) {   // v_cvt_pk_bf16_f32
    __hip_bfloat162 h = __float22bfloat162_rn(make_float2(a, b));
    return *(unsigned*)&h;
}
__device__ inline v8s ldsld8(const short* p) {
    return *(const v8s*)__builtin_assume_aligned(p, 16);
}
__device__ inline void g2lds16(const void* g, void* l) {
    __builtin_amdgcn_global_load_lds(
        (const __attribute__((address_space(1))) unsigned int*)g,
        (__attribute__((address_space(3))) unsigned int*)l, 16, 0, 0);
}

// ---------------------------------------------------------------------------
// Kernel 0: fragment-linear bf16 weight layouts + bf16 exp(trans) matrices
// + zero the atomic accumulators/counters (workspace is re-poisoned per iter).
// ---------------------------------------------------------------------------
__global__ void prep_kernel(const float* __restrict__ tr, const float* __restrict__ cw,
                            const float* __restrict__ fcw,
                            unsigned short* __restrict__ wB2,
                            unsigned short* __restrict__ fcwT2,
                            unsigned short* __restrict__ AT,
                            unsigned short* __restrict__ Ab,
                            float* __restrict__ accum, unsigned* __restrict__ cnt,
                            float* __restrict__ nllpart, unsigned* __restrict__ doneb)
{
    const int gid = blockIdx.x * 256 + threadIdx.x;
    const int gs  = 64 * 256;
    if (gid == 0) { *accum = 0.f; *cnt = 0u; }
    if (gid < BB) { nllpart[gid] = 0.f; doneb[gid] = 0u; }
    for (int idx = gid; idx < NCH * CKS * 8 * 512; idx += gs) {
        int e = idx & 7, p = (idx >> 3) & 63, blk = idx >> 9;
        int ch = blk / 24, rem = blk - ch * 24;
        int sl = rem >> 3, ft = rem & 7;
        int col = p >> 2, q = p & 3;
        int n  = ft * 16 + col;
        int gk = ch * 96 + sl * 32 + q * 8 + e;
        int kk = gk / 320, ee = gk - kk * 320;
        float v = (n < FF && ee < EE) ? cw[n * 900 + ee * 3 + kk] : 0.f;
        wB2[idx] = f2bf(v);
    }
    for (int idx = gid; idx < 16 * 512; idx += gs) {
        int e = idx & 7, p = (idx >> 3) & 63, blk = idx >> 9;
        int ks = blk >> 2, nt = blk & 3;
        int col = p >> 2, q = p & 3;
        int t = nt * 16 + col, f = ks * 32 + q * 8 + e;
        float v = (t < TT && f < FF) ? fcw[t * FF + f] : 0.f;
        fcwT2[idx] = f2bf(v);
    }
    for (int idx = gid; idx < 64 * 64; idx += gs) {
        int r = idx >> 6, c2 = idx & 63;
        AT[idx] = (r < TT && c2 < TT) ? f2bf(__expf(tr[c2 * TT + r])) : 0;
        Ab[idx] = (r < TT && c2 < TT) ? f2bf(__expf(tr[r * TT + c2])) : 0;
    }
}

// ---------------------------------------------------------------------------
// Kernel A: MFMA conv(K=3) + FC, with CRF numerator folded into the epilogue.
// grid (16, 32), 256 threads (4 waves). (unchanged -- passed rounds 1-2)
// ---------------------------------------------------------------------------
__global__ __launch_bounds__(256, 3) void emis_kernel(
    const int* __restrict__ x, const float* __restrict__ emb,
    const unsigned short* __restrict__ wB2, const float* __restrict__ cb,
    const unsigned short* __restrict__ fcwT2, const float* __restrict__ fcb,
    const int* __restrict__ tags, const float* __restrict__ tr,
    const float* __restrict__ start, const float* __restrict__ endt,
    float* __restrict__ expem, float* __restrict__ nllpart)
{
    __shared__ __align__(16) short ldsA[34 * AP];       // 22304 B (reused as feat)
    __shared__ __align__(16) short ldsB[CHB];           // 24576 B (weights)
    __shared__ float redN[2];

    const int b    = blockIdx.y;
    const int s0   = blockIdx.x * 32;
    const int tid  = threadIdx.x;
    const int wv   = tid >> 6;
    const int lane = tid & 63;
    const int col  = lane & 15;
    const int q    = lane >> 4;
    const int bofs = ((col << 2) | q) << 3;             // fragment-linear lane offset

#pragma unroll
    for (int it = 0; it < 6; ++it) {
        int seg = it * 4 + wv;
        g2lds16((const char*)wB2 + seg * 1024 + lane * 16,
                (char*)ldsB + seg * 1024);
    }

    int   xr[10], ofs[10], e0a[10];
#pragma unroll
    for (int it = 0; it < 10; ++it) {
        int g = tid + it * 256;
        int r = g / 75, eg = g - r * 75;
        int e0 = eg * 4;
        int src = s0 - 1 + r;
        bool v = (g < 2550) && (src >= 0) && (src < SS);
        xr[it]  = v ? x[b * SS + src] : -1;
        ofs[it] = r * AP + e0;
        e0a[it] = e0;
    }
    float4 vv[10];
#pragma unroll
    for (int it = 0; it < 10; ++it)
        vv[it] = (xr[it] >= 0)
               ? *(const float4*)(emb + (size_t)xr[it] * EE + e0a[it])
               : make_float4(0.f, 0.f, 0.f, 0.f);
#pragma unroll
    for (int it = 0; it < 10; ++it) {
        int g = tid + it * 256;
        if (g < 2550) {
            unsigned lo = pkbf2(vv[it].x, vv[it].y);
            unsigned hi = pkbf2(vv[it].z, vv[it].w);
            *(uint2*)&ldsA[ofs[it]] = make_uint2(lo, hi);
        }
    }
    if (tid < 34 * 5) {
        int r = tid / 5, c0 = 300 + (tid % 5) * 4;
        *(short4*)&ldsA[r * AP + c0] = make_short4(0, 0, 0, 0);
    }

    v4f acc[2][2];
#pragma unroll
    for (int a = 0; a < 2; ++a)
#pragma unroll
        for (int f = 0; f < 2; ++f) acc[a][f] = (v4f){0.f, 0.f, 0.f, 0.f};

    const int ftA = wv * 2, ftB = wv * 2 + 1;
    for (int ch = 0; ch < NCH; ++ch) {
        __syncthreads();
#pragma unroll
        for (int sl = 0; sl < CKS; ++sl) {
            int gk = ch * 96 + sl * 32;
            int kk = (gk >= 640) ? 2 : (gk >= 320 ? 1 : 0);
            int e0 = gk - kk * 320;
            v8s a0 = ldsld8(&ldsA[(col + kk) * AP + e0 + q * 8]);
            v8s a1 = ldsld8(&ldsA[(16 + col + kk) * AP + e0 + q * 8]);
            v8s b0 = ldsld8(&ldsB[((sl * 8 + ftA) << 9) + bofs]);
            v8s b1 = ldsld8(&ldsB[((sl * 8 + ftB) << 9) + bofs]);
            acc[0][0] = MFMA16(a0, b0, acc[0][0], 0, 0, 0);
            acc[0][1] = MFMA16(a0, b1, acc[0][1], 0, 0, 0);
            acc[1][0] = MFMA16(a1, b0, acc[1][0], 0, 0, 0);
            acc[1][1] = MFMA16(a1, b1, acc[1][1], 0, 0, 0);
        }
        __syncthreads();
        if (ch < NCH - 1) {
            const char* g = (const char*)(wB2 + (size_t)(ch + 1) * CHB);
#pragma unroll
            for (int it = 0; it < 6; ++it) {
                int seg = it * 4 + wv;
                g2lds16(g + seg * 1024 + lane * 16, (char*)ldsB + seg * 1024);
            }
        }
    }

    short* A2 = ldsA;
    short* B2 = ldsB;
#pragma unroll
    for (int it = 0; it < 4; ++it) {
        int seg = it * 4 + wv;
        g2lds16((const char*)fcwT2 + seg * 1024 + lane * 16,
                (char*)B2 + seg * 1024);
    }
#pragma unroll
    for (int st = 0; st < 2; ++st)
#pragma unroll
        for (int fi = 0; fi < 2; ++fi) {
            int f = (wv * 2 + fi) * 16 + col;
            float bias = (f < FF) ? cb[f] : 0.f;
#pragma unroll
            for (int rg = 0; rg < 4; ++rg) {
                int s = st * 16 + q * 4 + rg;
                float v = (f < FF) ? fmaxf(acc[st][fi][rg] + bias, 0.f) : 0.f;
                A2[s * A2P + f] = (short)f2bf(v);
            }
        }
    __syncthreads();

    if (wv < 2) {
        v4f a2[4];
#pragma unroll
        for (int nt = 0; nt < 4; ++nt) a2[nt] = (v4f){0.f, 0.f, 0.f, 0.f};
#pragma unroll
        for (int ks = 0; ks < 4; ++ks) {
            v8s af = ldsld8(&A2[(wv * 16 + col) * A2P + ks * 32 + q * 8]);
#pragma unroll
            for (int nt = 0; nt < 4; ++nt) {
                v8s bt = ldsld8(&B2[((ks * 4 + nt) << 9) + bofs]);
                a2[nt] = MFMA16(af, bt, a2[nt], 0, 0, 0);
            }
        }
        float fb0 = fcb[col], fb1 = fcb[16 + col], fb2 = fcb[32 + col];
        float fb3 = (col < 2) ? fcb[48 + col] : 0.f;
        float nllp = 0.f;
#pragma unroll
        for (int rg = 0; rg < 4; ++rg) {
            int s = s0 + wv * 16 + q * 4 + rg;
            float e0v = a2[0][rg] + fb0;
            float e1v = a2[1][rg] + fb1;
            float e2v = a2[2][rg] + fb2;
            float e3v = (col < 2) ? a2[3][rg] + fb3 : -1e30f;
            float m = fmaxf(fmaxf(e0v, e1v), fmaxf(e2v, e3v));
#pragma unroll
            for (int off = 1; off < 16; off <<= 1) m = fmaxf(m, __shfl_xor(m, off));
            int gidx = b * SS + s;
            int tg = tags[gidx];
            float* orow = expem + (size_t)gidx * TT;
            orow[col]      = __expf(e0v - m);
            orow[16 + col] = __expf(e1v - m);
            orow[32 + col] = __expf(e2v - m);
            if (col < 2) orow[48 + col] = __expf(e3v - m);
            if (tg == col)            nllp -= e0v;
            else if (tg == 16 + col)  nllp -= e1v;
            else if (tg == 32 + col)  nllp -= e2v;
            else if (col < 2 && tg == 48 + col) nllp -= e3v;
            if (col == 0) {
                nllp += m;
                if (s < SS - 1) nllp -= tr[tg * TT + tags[gidx + 1]];
                if (s == 0)      nllp -= start[tg];
                if (s == SS - 1) nllp -= endt[tg];
            }
        }
#pragma unroll
        for (int off = 1; off < 64; off <<= 1) nllp += __shfl_xor(nllp, off);
        if (lane == 0) redN[wv] = nllp;
    }
    __syncthreads();
    if (tid == 0) atomicAdd(nllpart + b, redN[0] + redN[1]);
}

// ---------------------------------------------------------------------------
// Chain helpers: spill-free dot (named accumulators, static indexing only).
// ---------------------------------------------------------------------------
__device__ inline float chaindot(const v8s (&buf)[8], const float* pvec) {
    const float4* pv4 = (const float4*)__builtin_assume_aligned(pvec, 16);
    float a0 = 0.f, a1 = 0.f, a2 = 0.f, a3 = 0.f;   // 4 chains: dep 256->64 cy
#pragma unroll
    for (int g = 0; g < 8; ++g) {
        v8s v = buf[g];
        float4 pA = pv4[g * 2], pB = pv4[g * 2 + 1];
        float* aa = (g & 3) == 0 ? &a0 : (g & 3) == 1 ? &a1 : (g & 3) == 2 ? &a2 : &a3;
        float t = *aa;
        t = fmaf(bf2f(v[0]), pA.x, t);
        t = fmaf(bf2f(v[1]), pA.y, t);
        t = fmaf(bf2f(v[2]), pA.z, t);
        t = fmaf(bf2f(v[3]), pA.w, t);
        t = fmaf(bf2f(v[4]), pB.x, t);
        t = fmaf(bf2f(v[5]), pB.y, t);
        t = fmaf(bf2f(v[6]), pB.z, t);
        t = fmaf(bf2f(v[7]), pB.w, t);
        *aa = t;
    }
    return (a0 + a1) + (a2 + a3);
}

__device__ inline void chainfin(float acc2, float* pvec, int i, float& logacc) {
    float mx = acc2;
#pragma unroll
    for (int off = 1; off < 64; off <<= 1) mx = fmaxf(mx, __shfl_xor(mx, off));
    mx = fmaxf(mx, 1e-37f);
    logacc += __logf(mx);
    pvec[i] = acc2 * (1.f / mx);
}

// ---------------------------------------------------------------------------
// Kernel B: round-0 structure -- per-(batch,chunk) product of 16 step
// matrices via MFMA, ONE wave per block (no barrier cost, 22.5 KB LDS ->
// 7 blocks/CU, whole grid resident in one scheduling round).
// Last chunk block of batch b runs the vector chain in-place (doneb
// protocol, proven rounds 1-2) -- with a REGISTER double-buffer (bufA/bufB,
// named + statically indexed, outer loop #pragma unroll 1) instead of the
// rb[4][8] array that spilled to scratch (VGPR_Count=68 < 128 needed).
// grid (NC, BB), 64 threads.
// ---------------------------------------------------------------------------
__global__ __launch_bounds__(64) void chunkchain_kernel(
    const float* __restrict__ expem, const unsigned short* __restrict__ AT,
    const unsigned short* __restrict__ Ab,
    unsigned short* __restrict__ R, float* __restrict__ lsR,
    const float* __restrict__ start, const float* __restrict__ endt,
    const float* __restrict__ nllpart, unsigned* __restrict__ doneb,
    float* __restrict__ accum, unsigned* __restrict__ cnt,
    float* __restrict__ out)
{
    __shared__ __align__(16) short L[2][64 * MP];   // 18432 B
    __shared__ __align__(16) float emL[CH][64];     // 4096 B
    const int c = blockIdx.x, b = blockIdx.y;
    const int lane = threadIdx.x;
    const int col = lane & 15, q = lane >> 4;
    const int t0 = c * CH + 1;
    const int nf = (c == NC - 1) ? (SS - 1 - (NC - 1) * CH) : CH;

    for (int idx = lane; idx < CH * 64; idx += 64) {
        int k = idx >> 6, m = idx & 63;
        float v = 0.f;
        if (m < TT && k < nf) v = expem[((size_t)(b * SS + t0 + k)) * TT + m];
        emL[k][m] = v;
    }

    v8s af[4][2];
#pragma unroll
    for (int jt = 0; jt < 4; ++jt)
#pragma unroll
        for (int kc = 0; kc < 2; ++kc)
            af[jt][kc] = *(const v8s*)(AT + (jt * 16 + col) * 64 + kc * 32 + q * 8);
    __syncthreads();

    {
        const v8s* arow = (const v8s*)(Ab + lane * 64);
#pragma unroll
        for (int g = 0; g < 8; ++g) {
            v8s a = arow[g];
            float f[8];
#pragma unroll
            for (int e = 0; e < 8; ++e) f[e] = bf2f(a[e]) * emL[0][g * 8 + e];
            uint4 o = make_uint4(pkbf2(f[0], f[1]), pkbf2(f[2], f[3]),
                                 pkbf2(f[4], f[5]), pkbf2(f[6], f[7]));
            *(uint4*)&L[0][lane * MP + g * 8] = o;
        }
    }

    int cur = 0;
    for (int k = 1; k < nf; ++k) {
        __syncthreads();
        v8s bf[4][2];
#pragma unroll
        for (int nt = 0; nt < 4; ++nt)
#pragma unroll
            for (int kc = 0; kc < 2; ++kc)
                bf[nt][kc] = ldsld8(&L[cur][(nt * 16 + col) * MP + kc * 32 + q * 8]);
        v4f acc[4][4];
#pragma unroll
        for (int jt = 0; jt < 4; ++jt)
#pragma unroll
            for (int nt = 0; nt < 4; ++nt) {
                acc[jt][nt] = (v4f){0.f, 0.f, 0.f, 0.f};
                acc[jt][nt] = MFMA16(af[jt][0], bf[nt][0], acc[jt][nt], 0, 0, 0);
                acc[jt][nt] = MFMA16(af[jt][1], bf[nt][1], acc[jt][nt], 0, 0, 0);
            }
        if (k < nf - 1) {
#pragma unroll
            for (int jt = 0; jt < 4; ++jt) {
                const float4 em4 = *(const float4*)&emL[k][jt * 16 + q * 4];
#pragma unroll
                for (int nt = 0; nt < 4; ++nt) {
                    uint2 o = make_uint2(
                        pkbf2(acc[jt][nt][0] * em4.x, acc[jt][nt][1] * em4.y),
                        pkbf2(acc[jt][nt][2] * em4.z, acc[jt][nt][3] * em4.w));
                    *(uint2*)&L[cur ^ 1][(nt * 16 + col) * MP + jt * 16 + q * 4] = o;
                }
            }
            cur ^= 1;
        } else {
            float vals[4][4][4];
            float mx = 0.f;
#pragma unroll
            for (int jt = 0; jt < 4; ++jt) {
                const float4 em4 = *(const float4*)&emL[k][jt * 16 + q * 4];
#pragma unroll
                for (int nt = 0; nt < 4; ++nt) {
                    vals[jt][nt][0] = acc[jt][nt][0] * em4.x;
                    vals[jt][nt][1] = acc[jt][nt][1] * em4.y;
                    vals[jt][nt][2] = acc[jt][nt][2] * em4.z;
                    vals[jt][nt][3] = acc[jt][nt][3] * em4.w;
#pragma unroll
                    for (int r = 0; r < 4; ++r) mx = fmaxf(mx, vals[jt][nt][r]);
                }
            }
#pragma unroll
            for (int off = 1; off < 64; off <<= 1) mx = fmaxf(mx, __shfl_xor(mx, off));
            mx = fmaxf(mx, 1e-37f);
            float inv = 1.f / mx;
            unsigned short* Rc = R + ((size_t)(b * NC + c) << 12);
#pragma unroll
            for (int jt = 0; jt < 4; ++jt)
#pragma unroll
                for (int nt = 0; nt < 4; ++nt)
#pragma unroll
                    for (int r = 0; r < 4; ++r)
                        Rc[(jt * 16 + q * 4 + r) * 64 + nt * 16 + col] =
                            f2bf(vals[jt][nt][r] * inv);
            if (lane == 0) lsR[b * NC + c] = __logf(mx);
        }
    }

    // ---- completion protocol: last chunk block of batch b runs the chain ----
    __threadfence();                           // release our R/lsR writes
    unsigned o = 0;
    if (lane == 0) o = atomicAdd(doneb + b, 1u);
    o = __shfl(o, 0);
    if (o != NC - 1u) return;

    __threadfence();                           // acquire
    const int i = lane;
    float* pvec = &emL[0][0];                  // reuse dead LDS
    pvec[i] = (i < TT) ? __expf(start[i]) * expem[((size_t)(b * SS)) * TT + i] : 0.f;
    float lsv = (i < NC) ? lsR[b * NC + i] : 0.f;   // hoist all 32 lsR reads
#pragma unroll
    for (int off = 1; off < 64; off <<= 1) lsv += __shfl_xor(lsv, off);

    const unsigned short* Rb = R + ((size_t)(b * NC) << 12);
    v8s bufA[8], bufB[8];                      // 64 VGPR register double-buffer
#pragma unroll
    for (int g = 0; g < 8; ++g)
        bufA[g] = *(const v8s*)(Rb + i * 64 + g * 8);
    float logacc = 0.f;
#pragma unroll 1
    for (int cc = 0; cc < NC; cc += 2) {
        const unsigned short* R1 = Rb + ((size_t)(cc + 1) << 12);
#pragma unroll
        for (int g = 0; g < 8; ++g)
            bufB[g] = *(const v8s*)(R1 + i * 64 + g * 8);
        float acc2 = chaindot(bufA, pvec);
        chainfin(acc2, pvec, i, logacc);
        if (cc + 2 < NC) {
            const unsigned short* R2 = Rb + ((size_t)(cc + 2) << 12);
#pragma unroll
            for (int g = 0; g < 8; ++g)
                bufA[g] = *(const v8s*)(R2 + i * 64 + g * 8);
        }
        acc2 = chaindot(bufB, pvec);
        chainfin(acc2, pvec, i, logacc);
    }
    float sv = (i < TT) ? pvec[i] * __expf(endt[i]) : 0.f;
#pragma unroll
    for (int off = 1; off < 64; off <<= 1) sv += __shfl_xor(sv, off);
    if (i == 0) {
        float nll = nllpart[b] + logacc + lsv + __logf(sv);
        atomicAdd(accum, nll);
        __threadfence();
        unsigned oo = atomicAdd(cnt, 1u);
        if (oo == BB - 1) out[0] = atomicAdd(accum, 0.f);
    }
}

extern "C" void kernel_launch(void* const* d_in, const int* in_sizes, int n_in,
                              void* d_out, int out_size, void* d_ws, size_t ws_size,
                              hipStream_t stream)
{
    const int*   x    = (const int*)d_in[0];
    const int*   tags = (const int*)d_in[1];
    const float* emb  = (const float*)d_in[2];
    const float* cw   = (const float*)d_in[3];
    const float* cb   = (const float*)d_in[4];
    const float* fcw  = (const float*)d_in[5];
    const float* fcb  = (const float*)d_in[6];
    const float* st   = (const float*)d_in[7];
    const float* en   = (const float*)d_in[8];
    const float* tr   = (const float*)d_in[9];

    unsigned short* wB2   = (unsigned short*)d_ws;            // 122880 sh
    unsigned short* fcwT2 = wB2 + NCH * CKS * 8 * 512;        // 8192 sh
    unsigned short* ATm   = fcwT2 + 16 * 512;                 // 4096 sh
    unsigned short* Abm   = ATm + 4096;                       // 4096 sh
    unsigned short* Rm    = Abm + 4096;                       // BB*NC*4096 sh = 8 MB
    float* fbase   = (float*)(Rm + (size_t)BB * NC * 4096);
    float* expem   = fbase;                                   // 819200
    float* lsR     = expem + (size_t)BB * SS * TT;            // 1024
    float* nllpart = lsR + BB * NC;                           // 32
    float* accum   = nllpart + BB;                            // 1
    unsigned* cnt  = (unsigned*)(accum + 1);                  // 1
    unsigned* doneb = cnt + 1;                                // 32

    prep_kernel<<<dim3(64), 256, 0, stream>>>(tr, cw, fcw, wB2, fcwT2, ATm, Abm,
                                              accum, cnt, nllpart, doneb);
    emis_kernel<<<dim3(16, BB), 256, 0, stream>>>(x, emb, wB2, cb, fcwT2, fcb,
                                                  tags, tr, st, en, expem, nllpart);
    chunkchain_kernel<<<dim3(NC, BB), 64, 0, stream>>>(expem, ATm, Abm, Rm, lsR,
                                                       st, en, nllpart, doneb,
                                                       accum, cnt, (float*)d_out);
}

// Round 4
// 239.689 us; speedup vs baseline: 1.2784x; 1.1976x over previous
//
#include <hip/hip_runtime.h>
#include <hip/hip_bf16.h>
#include <math.h>

#define BB 32
#define SS 512
#define EE 300
#define FF 100
#define TT 50
#define CH 16            // steps per chunk-product (15 multiplies, overflow-safe)
#define NC 32            // chunks = 512/16

typedef __attribute__((ext_vector_type(8))) short v8s;   // 8 bf16
typedef __attribute__((ext_vector_type(4))) float v4f;   // 4 f32
#define MFMA16 __builtin_amdgcn_mfma_f32_16x16x32_bf16

#define AP 328           // emb LDS stride (shorts): 164 words -> 2-way max (free)
#define NCH 10           // conv K-chunks of 96
#define CKS 3            // k-steps per chunk
#define CHB (128 * 96)   // shorts per conv B chunk buffer (24576 B)
#define A2P 136          // feat LDS stride (shorts): 68 words -> 2-way (free)
#define MP 72            // chunk-product LDS row stride (bf16)

__device__ inline unsigned short f2bf(float v) {
    unsigned u = __float_as_uint(v);
    unsigned r = u + 0x7fff + ((u >> 16) & 1);
    return (unsigned short)(r >> 16);
}
__device__ inline float bf2f(short s) {
    return __uint_as_float(((unsigned)(unsigned short)s) << 16);
}
__device__ inline unsigned pkbf2(float a, float b) {   // v_cvt_pk_bf16_f32
    __hip_bfloat162 h = __float22bfloat162_rn(make_float2(a, b));
    return *(unsigned*)&h;
}
__device__ inline v8s ldsld8(const short* p) {
    return *(const v8s*)__builtin_assume_aligned(p, 16);
}
__device__ inline void g2lds16(const void* g, void* l) {
    __builtin_amdgcn_global_load_lds(
        (const __attribute__((address_space(1))) unsigned int*)g,
        (__attribute__((address_space(3))) unsigned int*)l, 16, 0, 0);
}

// ---------------------------------------------------------------------------
// Kernel 0: fragment-linear bf16 weight layouts + bf16 exp(trans) matrices
// + zero the atomic accumulator/counter used by chain_kernel.  (R0 verbatim)
// ---------------------------------------------------------------------------
__global__ void prep_kernel(const float* __restrict__ tr, const float* __restrict__ cw,
                            const float* __restrict__ fcw,
                            unsigned short* __restrict__ wB2,
                            unsigned short* __restrict__ fcwT2,
                            unsigned short* __restrict__ AT,
                            unsigned short* __restrict__ Ab,
                            float* __restrict__ accum, unsigned* __restrict__ cnt)
{
    const int gid = blockIdx.x * 256 + threadIdx.x;
    const int gs  = 64 * 256;
    if (gid == 0) { *accum = 0.f; *cnt = 0u; }
    for (int idx = gid; idx < NCH * CKS * 8 * 512; idx += gs) {
        int e = idx & 7, p = (idx >> 3) & 63, blk = idx >> 9;
        int ch = blk / 24, rem = blk - ch * 24;
        int sl = rem >> 3, ft = rem & 7;
        int col = p >> 2, q = p & 3;
        int n  = ft * 16 + col;
        int gk = ch * 96 + sl * 32 + q * 8 + e;
        int kk = gk / 320, ee = gk - kk * 320;
        float v = (n < FF && ee < EE) ? cw[n * 900 + ee * 3 + kk] : 0.f;
        wB2[idx] = f2bf(v);
    }
    for (int idx = gid; idx < 16 * 512; idx += gs) {
        int e = idx & 7, p = (idx >> 3) & 63, blk = idx >> 9;
        int ks = blk >> 2, nt = blk & 3;
        int col = p >> 2, q = p & 3;
        int t = nt * 16 + col, f = ks * 32 + q * 8 + e;
        float v = (t < TT && f < FF) ? fcw[t * FF + f] : 0.f;
        fcwT2[idx] = f2bf(v);
    }
    for (int idx = gid; idx < 64 * 64; idx += gs) {
        int r = idx >> 6, c2 = idx & 63;
        AT[idx] = (r < TT && c2 < TT) ? f2bf(__expf(tr[c2 * TT + r])) : 0;
        Ab[idx] = (r < TT && c2 < TT) ? f2bf(__expf(tr[r * TT + c2])) : 0;
    }
}

// ---------------------------------------------------------------------------
// Kernel A: MFMA conv(K=3) + FC.  CHANGE vs R0: double-buffered weight DMA
// (ldsB[2], 71.5 KB LDS -> 2 blocks/CU, 512 blocks = all resident).  The DMA
// for chunk ch+1 is issued BEFORE the MFMAs of chunk ch, so its latency hides
// under compute; one barrier per chunk instead of two.  FC-weight DMA issues
// during the last conv chunk.  Everything else is R0 verbatim.
// grid (16, 32), 256 threads (4 waves).
// ---------------------------------------------------------------------------
__global__ __launch_bounds__(256, 2) void emis_kernel(
    const int* __restrict__ x, const float* __restrict__ emb,
    const unsigned short* __restrict__ wB2, const float* __restrict__ cb,
    const unsigned short* __restrict__ fcwT2, const float* __restrict__ fcb,
    const int* __restrict__ tags,
    float* __restrict__ expem, float* __restrict__ rmv, float* __restrict__ emtag)
{
    __shared__ __align__(16) short ldsA[34 * AP];       // 22304 B (reused as feat)
    __shared__ __align__(16) short ldsB[2 * CHB];       // 49152 B (weight dbuf)

    const int b    = blockIdx.y;
    const int s0   = blockIdx.x * 32;
    const int tid  = threadIdx.x;
    const int wv   = tid >> 6;
    const int lane = tid & 63;
    const int col  = lane & 15;
    const int q    = lane >> 4;
    const int bofs = ((col << 2) | q) << 3;             // fragment-linear lane offset

    // DMA conv chunk 0 into buffer 0 (overlaps the A-gather below)
#pragma unroll
    for (int it = 0; it < 6; ++it) {
        int seg = it * 4 + wv;
        g2lds16((const char*)wB2 + seg * 1024 + lane * 16,
                (char*)ldsB + seg * 1024);
    }

    // ---- stage A with explicit MLP: all x-loads, then all emb gathers ----
    int   xr[10], ofs[10], e0a[10];
#pragma unroll
    for (int it = 0; it < 10; ++it) {
        int g = tid + it * 256;
        int r = g / 75, eg = g - r * 75;
        int e0 = eg * 4;
        int src = s0 - 1 + r;
        bool v = (g < 2550) && (src >= 0) && (src < SS);
        xr[it]  = v ? x[b * SS + src] : -1;
        ofs[it] = r * AP + e0;
        e0a[it] = e0;
    }
    float4 vv[10];
#pragma unroll
    for (int it = 0; it < 10; ++it)
        vv[it] = (xr[it] >= 0)
               ? *(const float4*)(emb + (size_t)xr[it] * EE + e0a[it])
               : make_float4(0.f, 0.f, 0.f, 0.f);
#pragma unroll
    for (int it = 0; it < 10; ++it) {
        int g = tid + it * 256;
        if (g < 2550) {
            unsigned lo = pkbf2(vv[it].x, vv[it].y);
            unsigned hi = pkbf2(vv[it].z, vv[it].w);
            *(uint2*)&ldsA[ofs[it]] = make_uint2(lo, hi);
        }
    }
    if (tid < 34 * 5) {
        int r = tid / 5, c0 = 300 + (tid % 5) * 4;
        *(short4*)&ldsA[r * AP + c0] = make_short4(0, 0, 0, 0);
    }

    v4f acc[2][2];
#pragma unroll
    for (int a = 0; a < 2; ++a)
#pragma unroll
        for (int f = 0; f < 2; ++f) acc[a][f] = (v4f){0.f, 0.f, 0.f, 0.f};

    const int ftA = wv * 2, ftB = wv * 2 + 1;
    for (int ch = 0; ch < NCH; ++ch) {
        __syncthreads();   // drains DMA for ch; all reads of the other buf done
        if (ch < NCH - 1) {        // prefetch chunk ch+1 into the other buffer
            const char* g = (const char*)(wB2 + (size_t)(ch + 1) * CHB);
            char* l = (char*)ldsB + ((ch + 1) & 1) * (CHB * 2);
#pragma unroll
            for (int it = 0; it < 6; ++it) {
                int seg = it * 4 + wv;
                g2lds16(g + seg * 1024 + lane * 16, l + seg * 1024);
            }
        } else {                   // last chunk: prefetch FC weights into buf 0
#pragma unroll
            for (int it = 0; it < 4; ++it) {
                int seg = it * 4 + wv;
                g2lds16((const char*)fcwT2 + seg * 1024 + lane * 16,
                        (char*)ldsB + seg * 1024);
            }
        }
        const short* Bc = ldsB + (ch & 1) * CHB;
#pragma unroll
        for (int sl = 0; sl < CKS; ++sl) {
            int gk = ch * 96 + sl * 32;
            int kk = (gk >= 640) ? 2 : (gk >= 320 ? 1 : 0);
            int e0 = gk - kk * 320;
            v8s a0 = ldsld8(&ldsA[(col + kk) * AP + e0 + q * 8]);
            v8s a1 = ldsld8(&ldsA[(16 + col + kk) * AP + e0 + q * 8]);
            v8s b0 = ldsld8(&Bc[((sl * 8 + ftA) << 9) + bofs]);
            v8s b1 = ldsld8(&Bc[((sl * 8 + ftB) << 9) + bofs]);
            acc[0][0] = MFMA16(a0, b0, acc[0][0], 0, 0, 0);
            acc[0][1] = MFMA16(a0, b1, acc[0][1], 0, 0, 0);
            acc[1][0] = MFMA16(a1, b0, acc[1][0], 0, 0, 0);
            acc[1][1] = MFMA16(a1, b1, acc[1][1], 0, 0, 0);
        }
    }
    __syncthreads();   // drains FC DMA; all conv reads of ldsA/ldsB finished

    // feat (bias+relu, bf16) into ldsA (dead); FC weights already in ldsB[0]
    short* A2 = ldsA;
    short* B2 = ldsB;
#pragma unroll
    for (int st = 0; st < 2; ++st)
#pragma unroll
        for (int fi = 0; fi < 2; ++fi) {
            int f = (wv * 2 + fi) * 16 + col;
            float bias = (f < FF) ? cb[f] : 0.f;
#pragma unroll
            for (int rg = 0; rg < 4; ++rg) {
                int s = st * 16 + q * 4 + rg;
                float v = (f < FF) ? fmaxf(acc[st][fi][rg] + bias, 0.f) : 0.f;
                A2[s * A2P + f] = (short)f2bf(v);
            }
        }
    __syncthreads();

    // FC MFMA + epilogue (waves 0,1; wave = s-tile)
    if (wv < 2) {
        v4f a2[4];
#pragma unroll
        for (int nt = 0; nt < 4; ++nt) a2[nt] = (v4f){0.f, 0.f, 0.f, 0.f};
#pragma unroll
        for (int ks = 0; ks < 4; ++ks) {
            v8s af = ldsld8(&A2[(wv * 16 + col) * A2P + ks * 32 + q * 8]);
#pragma unroll
            for (int nt = 0; nt < 4; ++nt) {
                v8s bt = ldsld8(&B2[((ks * 4 + nt) << 9) + bofs]);
                a2[nt] = MFMA16(af, bt, a2[nt], 0, 0, 0);
            }
        }
        float fb0 = fcb[col], fb1 = fcb[16 + col], fb2 = fcb[32 + col];
        float fb3 = (col < 2) ? fcb[48 + col] : 0.f;
#pragma unroll
        for (int rg = 0; rg < 4; ++rg) {
            int s = s0 + wv * 16 + q * 4 + rg;
            float e0v = a2[0][rg] + fb0;
            float e1v = a2[1][rg] + fb1;
            float e2v = a2[2][rg] + fb2;
            float e3v = (col < 2) ? a2[3][rg] + fb3 : -1e30f;
            float m = fmaxf(fmaxf(e0v, e1v), fmaxf(e2v, e3v));
#pragma unroll
            for (int off = 1; off < 16; off <<= 1) m = fmaxf(m, __shfl_xor(m, off));
            int gidx = b * SS + s;
            if (col == 0) rmv[gidx] = m;
            int tg = tags[gidx];
            float* orow = expem + (size_t)gidx * TT;
            orow[col]      = __expf(e0v - m);
            orow[16 + col] = __expf(e1v - m);
            orow[32 + col] = __expf(e2v - m);
            if (col < 2) orow[48 + col] = __expf(e3v - m);
            if (tg == col)            emtag[gidx] = e0v;
            else if (tg == 16 + col)  emtag[gidx] = e1v;
            else if (tg == 32 + col)  emtag[gidx] = e2v;
            else if (col < 2 && tg == 48 + col) emtag[gidx] = e3v;
        }
    }
}

// ---------------------------------------------------------------------------
// Kernel B1: per-(batch,chunk) product of 16 step matrices via MFMA.
// (R0 verbatim -- the fastest measured configuration of this phase.)
// ---------------------------------------------------------------------------
__global__ __launch_bounds__(64) void chunk_kernel(
    const float* __restrict__ expem, const unsigned short* __restrict__ AT,
    const unsigned short* __restrict__ Ab,
    unsigned short* __restrict__ R, float* __restrict__ lsR)
{
    __shared__ __align__(16) short L[2][64 * MP];
    __shared__ __align__(16) float emL[CH][64];
    const int c = blockIdx.x, b = blockIdx.y;
    const int lane = threadIdx.x;
    const int col = lane & 15, q = lane >> 4;
    const int t0 = c * CH + 1;
    const int nf = (c == NC - 1) ? (SS - 1 - (NC - 1) * CH) : CH;

    for (int idx = lane; idx < CH * 64; idx += 64) {
        int k = idx >> 6, m = idx & 63;
        float v = 0.f;
        if (m < TT && k < nf) v = expem[((size_t)(b * SS + t0 + k)) * TT + m];
        emL[k][m] = v;
    }

    v8s af[4][2];
#pragma unroll
    for (int jt = 0; jt < 4; ++jt)
#pragma unroll
        for (int kc = 0; kc < 2; ++kc)
            af[jt][kc] = *(const v8s*)(AT + (jt * 16 + col) * 64 + kc * 32 + q * 8);
    __syncthreads();

    {
        const v8s* arow = (const v8s*)(Ab + lane * 64);
#pragma unroll
        for (int g = 0; g < 8; ++g) {
            v8s a = arow[g];
            float f[8];
#pragma unroll
            for (int e = 0; e < 8; ++e) f[e] = bf2f(a[e]) * emL[0][g * 8 + e];
            uint4 o = make_uint4(pkbf2(f[0], f[1]), pkbf2(f[2], f[3]),
                                 pkbf2(f[4], f[5]), pkbf2(f[6], f[7]));
            *(uint4*)&L[0][lane * MP + g * 8] = o;
        }
    }

    int cur = 0;
    for (int k = 1; k < nf; ++k) {
        __syncthreads();
        v8s bf[4][2];
#pragma unroll
        for (int nt = 0; nt < 4; ++nt)
#pragma unroll
            for (int kc = 0; kc < 2; ++kc)
                bf[nt][kc] = ldsld8(&L[cur][(nt * 16 + col) * MP + kc * 32 + q * 8]);
        v4f acc[4][4];
#pragma unroll
        for (int jt = 0; jt < 4; ++jt)
#pragma unroll
            for (int nt = 0; nt < 4; ++nt) {
                acc[jt][nt] = (v4f){0.f, 0.f, 0.f, 0.f};
                acc[jt][nt] = MFMA16(af[jt][0], bf[nt][0], acc[jt][nt], 0, 0, 0);
                acc[jt][nt] = MFMA16(af[jt][1], bf[nt][1], acc[jt][nt], 0, 0, 0);
            }
        if (k < nf - 1) {
#pragma unroll
            for (int jt = 0; jt < 4; ++jt) {
                const float4 em4 = *(const float4*)&emL[k][jt * 16 + q * 4];
#pragma unroll
                for (int nt = 0; nt < 4; ++nt) {
                    uint2 o = make_uint2(
                        pkbf2(acc[jt][nt][0] * em4.x, acc[jt][nt][1] * em4.y),
                        pkbf2(acc[jt][nt][2] * em4.z, acc[jt][nt][3] * em4.w));
                    *(uint2*)&L[cur ^ 1][(nt * 16 + col) * MP + jt * 16 + q * 4] = o;
                }
            }
            cur ^= 1;
        } else {
            float vals[4][4][4];
            float mx = 0.f;
#pragma unroll
            for (int jt = 0; jt < 4; ++jt) {
                const float4 em4 = *(const float4*)&emL[k][jt * 16 + q * 4];
#pragma unroll
                for (int nt = 0; nt < 4; ++nt) {
                    vals[jt][nt][0] = acc[jt][nt][0] * em4.x;
                    vals[jt][nt][1] = acc[jt][nt][1] * em4.y;
                    vals[jt][nt][2] = acc[jt][nt][2] * em4.z;
                    vals[jt][nt][3] = acc[jt][nt][3] * em4.w;
#pragma unroll
                    for (int r = 0; r < 4; ++r) mx = fmaxf(mx, vals[jt][nt][r]);
                }
            }
#pragma unroll
            for (int off = 1; off < 64; off <<= 1) mx = fmaxf(mx, __shfl_xor(mx, off));
            mx = fmaxf(mx, 1e-37f);
            float inv = 1.f / mx;
            unsigned short* Rc = R + ((size_t)(b * NC + c) << 12);
#pragma unroll
            for (int jt = 0; jt < 4; ++jt)
#pragma unroll
                for (int nt = 0; nt < 4; ++nt)
#pragma unroll
                    for (int r = 0; r < 4; ++r)
                        Rc[(jt * 16 + q * 4 + r) * 64 + nt * 16 + col] =
                            f2bf(vals[jt][nt][r] * inv);
            if (lane == 0) lsR[b * NC + c] = __logf(mx);
        }
    }
}

// ---------------------------------------------------------------------------
// Chain helpers: spill-free dot (named accumulators, static indexing only).
// ---------------------------------------------------------------------------
__device__ inline float chaindot(const v8s (&buf)[8], const float* pvec) {
    const float4* pv4 = (const float4*)__builtin_assume_aligned(pvec, 16);
    float a0 = 0.f, a1 = 0.f, a2 = 0.f, a3 = 0.f;   // 4 chains: dep 256->64 cy
#pragma unroll
    for (int g = 0; g < 8; ++g) {
        v8s v = buf[g];
        float4 pA = pv4[g * 2], pB = pv4[g * 2 + 1];
        float* aa = (g & 3) == 0 ? &a0 : (g & 3) == 1 ? &a1 : (g & 3) == 2 ? &a2 : &a3;
        float t = *aa;
        t = fmaf(bf2f(v[0]), pA.x, t);
        t = fmaf(bf2f(v[1]), pA.y, t);
        t = fmaf(bf2f(v[2]), pA.z, t);
        t = fmaf(bf2f(v[3]), pA.w, t);
        t = fmaf(bf2f(v[4]), pB.x, t);
        t = fmaf(bf2f(v[5]), pB.y, t);
        t = fmaf(bf2f(v[6]), pB.z, t);
        t = fmaf(bf2f(v[7]), pB.w, t);
        *aa = t;
    }
    return (a0 + a1) + (a2 + a3);
}

__device__ inline void chainfin(float acc2, float* pvec, int i, float& logacc) {
    float mx = acc2;
#pragma unroll
    for (int off = 1; off < 64; off <<= 1) mx = fmaxf(mx, __shfl_xor(mx, off));
    mx = fmaxf(mx, 1e-37f);
    logacc += __logf(mx);
    pvec[i] = acc2 * (1.f / mx);
}

// ---------------------------------------------------------------------------
// Kernel B2: chain + numerator + atomic finish.  R0 structure (separate
// dispatch, 256 threads: wave 0 chain, waves 1-3 numerator) with the chain
// prefetch converted to the register double-buffer proven in round 3
// (bufA/bufB, named + statically indexed, outer loop #pragma unroll 1 --
// the R0 rb[3][8] array spilled to scratch) and the 32 lsR loads hoisted
// into one wave-reduce.  grid BB, 256 threads.
// ---------------------------------------------------------------------------
__global__ __launch_bounds__(256) void chain_kernel(
    const float* __restrict__ expem, const unsigned short* __restrict__ R,
    const float* __restrict__ lsR, const float* __restrict__ start,
    const float* __restrict__ endt,
    const float* __restrict__ emtag, const float* __restrict__ rmv,
    const int* __restrict__ tags, const float* __restrict__ tr,
    float* __restrict__ accum, unsigned* __restrict__ cnt,
    float* __restrict__ out)
{
    __shared__ __align__(16) float pvec[64];
    __shared__ float red[8];
    __shared__ float lzsh;
    const int b = blockIdx.x, tid = threadIdx.x;
    const int wv = tid >> 6, i = tid & 63;

    if (wv == 0) {
        pvec[i] = (i < TT) ? __expf(start[i]) * expem[((size_t)(b * SS)) * TT + i] : 0.f;
        float lsv = (i < NC) ? lsR[b * NC + i] : 0.f;   // hoist all 32 lsR reads
#pragma unroll
        for (int off = 1; off < 64; off <<= 1) lsv += __shfl_xor(lsv, off);

        const unsigned short* Rb = R + ((size_t)(b * NC) << 12);
        v8s bufA[8], bufB[8];                  // 64 VGPR register double-buffer
#pragma unroll
        for (int g = 0; g < 8; ++g)
            bufA[g] = *(const v8s*)(Rb + i * 64 + g * 8);
        float logacc = 0.f;
#pragma unroll 1
        for (int cc = 0; cc < NC; cc += 2) {
            const unsigned short* R1 = Rb + ((size_t)(cc + 1) << 12);
#pragma unroll
            for (int g = 0; g < 8; ++g)
                bufB[g] = *(const v8s*)(R1 + i * 64 + g * 8);
            float acc2 = chaindot(bufA, pvec);
            chainfin(acc2, pvec, i, logacc);
            if (cc + 2 < NC) {
                const unsigned short* R2 = Rb + ((size_t)(cc + 2) << 12);
#pragma unroll
                for (int g = 0; g < 8; ++g)
                    bufA[g] = *(const v8s*)(R2 + i * 64 + g * 8);
            }
            acc2 = chaindot(bufB, pvec);
            chainfin(acc2, pvec, i, logacc);
        }
        float sv = (i < TT) ? pvec[i] * __expf(endt[i]) : 0.f;
#pragma unroll
        for (int off = 1; off < 64; off <<= 1) sv += __shfl_xor(sv, off);
        if (i == 0) lzsh = logacc + lsv + __logf(sv);
    } else {
        float accN = 0.f, accR = 0.f;
        for (int s = tid - 64; s < SS; s += 192) {
            int gi = b * SS + s;
            accN += emtag[gi];
            accR += rmv[gi];
            int tg = tags[gi];
            if (s < SS - 1) accN += tr[tg * TT + tags[gi + 1]];
        }
#pragma unroll
        for (int off = 1; off < 64; off <<= 1) {
            accN += __shfl_xor(accN, off);
            accR += __shfl_xor(accR, off);
        }
        if (i == 0) { red[wv] = accN; red[4 + wv] = accR; }
    }
    __syncthreads();
    if (tid == 0) {
        float tn  = red[1] + red[2] + red[3];
        float trm = red[5] + red[6] + red[7];
        float num = tn + start[tags[b * SS]] + endt[tags[b * SS + SS - 1]];
        float nll = trm + lzsh - num;
        atomicAdd(accum, nll);
        __threadfence();
        unsigned old = atomicAdd(cnt, 1u);
        if (old == BB - 1) out[0] = atomicAdd(accum, 0.f);
    }
}

extern "C" void kernel_launch(void* const* d_in, const int* in_sizes, int n_in,
                              void* d_out, int out_size, void* d_ws, size_t ws_size,
                              hipStream_t stream)
{
    const int*   x    = (const int*)d_in[0];
    const int*   tags = (const int*)d_in[1];
    const float* emb  = (const float*)d_in[2];
    const float* cw   = (const float*)d_in[3];
    const float* cb   = (const float*)d_in[4];
    const float* fcw  = (const float*)d_in[5];
    const float* fcb  = (const float*)d_in[6];
    const float* st   = (const float*)d_in[7];
    const float* en   = (const float*)d_in[8];
    const float* tr   = (const float*)d_in[9];

    unsigned short* wB2   = (unsigned short*)d_ws;            // 122880 sh
    unsigned short* fcwT2 = wB2 + NCH * CKS * 8 * 512;        // 8192 sh
    unsigned short* ATm   = fcwT2 + 16 * 512;                 // 4096 sh
    unsigned short* Abm   = ATm + 4096;                       // 4096 sh
    unsigned short* Rm    = Abm + 4096;                       // BB*NC*4096 sh = 8 MB
    float* fbase   = (float*)(Rm + (size_t)BB * NC * 4096);
    float* expem   = fbase;                                   // 819200
    float* rmv     = expem + (size_t)BB * SS * TT;            // 16384
    float* emtag   = rmv + BB * SS;                           // 16384
    float* lsR     = emtag + BB * SS;                         // 1024
    float* accum   = lsR + BB * NC;                           // 1
    unsigned* cnt  = (unsigned*)(accum + 1);                  // 1

    prep_kernel<<<dim3(64), 256, 0, stream>>>(tr, cw, fcw, wB2, fcwT2, ATm, Abm,
                                              accum, cnt);
    emis_kernel<<<dim3(16, BB), 256, 0, stream>>>(x, emb, wB2, cb, fcwT2, fcb,
                                                  tags, expem, rmv, emtag);
    chunk_kernel<<<dim3(NC, BB), 64, 0, stream>>>(expem, ATm, Abm, Rm, lsR);
    chain_kernel<<<dim3(BB), 256, 0, stream>>>(expem, Rm, lsR, st, en,
                                               emtag, rmv, tags, tr,
                                               accum, cnt, (float*)d_out);
}

// Round 5
// 237.892 us; speedup vs baseline: 1.2881x; 1.0076x over previous
//
#include <hip/hip_runtime.h>
#include <hip/hip_bf16.h>
#include <math.h>

#define BB 32
#define SS 512
#define EE 300
#define FF 100
#define TT 50
#define CH 16            // steps per chunk-product (15 multiplies, overflow-safe)
#define NC 32            // chunks = 512/16

typedef __attribute__((ext_vector_type(8))) short v8s;   // 8 bf16
typedef __attribute__((ext_vector_type(4))) float v4f;   // 4 f32
#define MFMA16 __builtin_amdgcn_mfma_f32_16x16x32_bf16

#define AP 328           // emb LDS stride (shorts): 164 words -> 2-way max (free)
#define NCH 10           // conv K-chunks of 96
#define CKS 3            // k-steps per chunk
#define CHB (128 * 96)   // shorts per conv B chunk buffer (24576 B)
#define A2P 136          // feat LDS stride (shorts): 68 words -> 2-way (free)
#define MP 72            // chunk-product LDS row stride (bf16)

__device__ inline unsigned short f2bf(float v) {
    unsigned u = __float_as_uint(v);
    unsigned r = u + 0x7fff + ((u >> 16) & 1);
    return (unsigned short)(r >> 16);
}
__device__ inline float bf2f(short s) {
    return __uint_as_float(((unsigned)(unsigned short)s) << 16);
}
__device__ inline unsigned pkbf2(float a, float b) {   // v_cvt_pk_bf16_f32
    __hip_bfloat162 h = __float22bfloat162_rn(make_float2(a, b));
    return *(unsigned*)&h;
}
__device__ inline v8s ldsld8(const short* p) {
    return *(const v8s*)__builtin_assume_aligned(p, 16);
}
__device__ inline void g2lds16(const void* g, void* l) {
    __builtin_amdgcn_global_load_lds(
        (const __attribute__((address_space(1))) unsigned int*)g,
        (__attribute__((address_space(3))) unsigned int*)l, 16, 0, 0);
}
// Wave-local LDS visibility (cross-lane within ONE wave): drain lgkmcnt.
// No s_barrier -- the two waves in a block are fully independent here.
__device__ inline void wavesync() {
    __builtin_amdgcn_sched_barrier(0);
    asm volatile("s_waitcnt lgkmcnt(0)" ::: "memory");
    __builtin_amdgcn_sched_barrier(0);
}

// ---------------------------------------------------------------------------
// Kernel 0: fragment-linear bf16 weight layouts + bf16 exp(trans) matrices
// + zero the atomic accumulator/counter used by chain_kernel.  (R0 verbatim)
// ---------------------------------------------------------------------------
__global__ void prep_kernel(const float* __restrict__ tr, const float* __restrict__ cw,
                            const float* __restrict__ fcw,
                            unsigned short* __restrict__ wB2,
                            unsigned short* __restrict__ fcwT2,
                            unsigned short* __restrict__ AT,
                            unsigned short* __restrict__ Ab,
                            float* __restrict__ accum, unsigned* __restrict__ cnt)
{
    const int gid = blockIdx.x * 256 + threadIdx.x;
    const int gs  = 64 * 256;
    if (gid == 0) { *accum = 0.f; *cnt = 0u; }
    for (int idx = gid; idx < NCH * CKS * 8 * 512; idx += gs) {
        int e = idx & 7, p = (idx >> 3) & 63, blk = idx >> 9;
        int ch = blk / 24, rem = blk - ch * 24;
        int sl = rem >> 3, ft = rem & 7;
        int col = p >> 2, q = p & 3;
        int n  = ft * 16 + col;
        int gk = ch * 96 + sl * 32 + q * 8 + e;
        int kk = gk / 320, ee = gk - kk * 320;
        float v = (n < FF && ee < EE) ? cw[n * 900 + ee * 3 + kk] : 0.f;
        wB2[idx] = f2bf(v);
    }
    for (int idx = gid; idx < 16 * 512; idx += gs) {
        int e = idx & 7, p = (idx >> 3) & 63, blk = idx >> 9;
        int ks = blk >> 2, nt = blk & 3;
        int col = p >> 2, q = p & 3;
        int t = nt * 16 + col, f = ks * 32 + q * 8 + e;
        float v = (t < TT && f < FF) ? fcw[t * FF + f] : 0.f;
        fcwT2[idx] = f2bf(v);
    }
    for (int idx = gid; idx < 64 * 64; idx += gs) {
        int r = idx >> 6, c2 = idx & 63;
        AT[idx] = (r < TT && c2 < TT) ? f2bf(__expf(tr[c2 * TT + r])) : 0;
        Ab[idx] = (r < TT && c2 < TT) ? f2bf(__expf(tr[r * TT + c2])) : 0;
    }
}

// ---------------------------------------------------------------------------
// Kernel A: MFMA conv(K=3) + FC, double-buffered weight DMA.  (R4 verbatim)
// grid (16, 32), 256 threads (4 waves).
// ---------------------------------------------------------------------------
__global__ __launch_bounds__(256, 2) void emis_kernel(
    const int* __restrict__ x, const float* __restrict__ emb,
    const unsigned short* __restrict__ wB2, const float* __restrict__ cb,
    const unsigned short* __restrict__ fcwT2, const float* __restrict__ fcb,
    const int* __restrict__ tags,
    float* __restrict__ expem, float* __restrict__ rmv, float* __restrict__ emtag)
{
    __shared__ __align__(16) short ldsA[34 * AP];       // 22304 B (reused as feat)
    __shared__ __align__(16) short ldsB[2 * CHB];       // 49152 B (weight dbuf)

    const int b    = blockIdx.y;
    const int s0   = blockIdx.x * 32;
    const int tid  = threadIdx.x;
    const int wv   = tid >> 6;
    const int lane = tid & 63;
    const int col  = lane & 15;
    const int q    = lane >> 4;
    const int bofs = ((col << 2) | q) << 3;             // fragment-linear lane offset

    // DMA conv chunk 0 into buffer 0 (overlaps the A-gather below)
#pragma unroll
    for (int it = 0; it < 6; ++it) {
        int seg = it * 4 + wv;
        g2lds16((const char*)wB2 + seg * 1024 + lane * 16,
                (char*)ldsB + seg * 1024);
    }

    // ---- stage A with explicit MLP: all x-loads, then all emb gathers ----
    int   xr[10], ofs[10], e0a[10];
#pragma unroll
    for (int it = 0; it < 10; ++it) {
        int g = tid + it * 256;
        int r = g / 75, eg = g - r * 75;
        int e0 = eg * 4;
        int src = s0 - 1 + r;
        bool v = (g < 2550) && (src >= 0) && (src < SS);
        xr[it]  = v ? x[b * SS + src] : -1;
        ofs[it] = r * AP + e0;
        e0a[it] = e0;
    }
    float4 vv[10];
#pragma unroll
    for (int it = 0; it < 10; ++it)
        vv[it] = (xr[it] >= 0)
               ? *(const float4*)(emb + (size_t)xr[it] * EE + e0a[it])
               : make_float4(0.f, 0.f, 0.f, 0.f);
#pragma unroll
    for (int it = 0; it < 10; ++it) {
        int g = tid + it * 256;
        if (g < 2550) {
            unsigned lo = pkbf2(vv[it].x, vv[it].y);
            unsigned hi = pkbf2(vv[it].z, vv[it].w);
            *(uint2*)&ldsA[ofs[it]] = make_uint2(lo, hi);
        }
    }
    if (tid < 34 * 5) {
        int r = tid / 5, c0 = 300 + (tid % 5) * 4;
        *(short4*)&ldsA[r * AP + c0] = make_short4(0, 0, 0, 0);
    }

    v4f acc[2][2];
#pragma unroll
    for (int a = 0; a < 2; ++a)
#pragma unroll
        for (int f = 0; f < 2; ++f) acc[a][f] = (v4f){0.f, 0.f, 0.f, 0.f};

    const int ftA = wv * 2, ftB = wv * 2 + 1;
    for (int ch = 0; ch < NCH; ++ch) {
        __syncthreads();   // drains DMA for ch; all reads of the other buf done
        if (ch < NCH - 1) {        // prefetch chunk ch+1 into the other buffer
            const char* g = (const char*)(wB2 + (size_t)(ch + 1) * CHB);
            char* l = (char*)ldsB + ((ch + 1) & 1) * (CHB * 2);
#pragma unroll
            for (int it = 0; it < 6; ++it) {
                int seg = it * 4 + wv;
                g2lds16(g + seg * 1024 + lane * 16, l + seg * 1024);
            }
        } else {                   // last chunk: prefetch FC weights into buf 0
#pragma unroll
            for (int it = 0; it < 4; ++it) {
                int seg = it * 4 + wv;
                g2lds16((const char*)fcwT2 + seg * 1024 + lane * 16,
                        (char*)ldsB + seg * 1024);
            }
        }
        const short* Bc = ldsB + (ch & 1) * CHB;
#pragma unroll
        for (int sl = 0; sl < CKS; ++sl) {
            int gk = ch * 96 + sl * 32;
            int kk = (gk >= 640) ? 2 : (gk >= 320 ? 1 : 0);
            int e0 = gk - kk * 320;
            v8s a0 = ldsld8(&ldsA[(col + kk) * AP + e0 + q * 8]);
            v8s a1 = ldsld8(&ldsA[(16 + col + kk) * AP + e0 + q * 8]);
            v8s b0 = ldsld8(&Bc[((sl * 8 + ftA) << 9) + bofs]);
            v8s b1 = ldsld8(&Bc[((sl * 8 + ftB) << 9) + bofs]);
            acc[0][0] = MFMA16(a0, b0, acc[0][0], 0, 0, 0);
            acc[0][1] = MFMA16(a0, b1, acc[0][1], 0, 0, 0);
            acc[1][0] = MFMA16(a1, b0, acc[1][0], 0, 0, 0);
            acc[1][1] = MFMA16(a1, b1, acc[1][1], 0, 0, 0);
        }
    }
    __syncthreads();   // drains FC DMA; all conv reads of ldsA/ldsB finished

    // feat (bias+relu, bf16) into ldsA (dead); FC weights already in ldsB[0]
    short* A2 = ldsA;
    short* B2 = ldsB;
#pragma unroll
    for (int st = 0; st < 2; ++st)
#pragma unroll
        for (int fi = 0; fi < 2; ++fi) {
            int f = (wv * 2 + fi) * 16 + col;
            float bias = (f < FF) ? cb[f] : 0.f;
#pragma unroll
            for (int rg = 0; rg < 4; ++rg) {
                int s = st * 16 + q * 4 + rg;
                float v = (f < FF) ? fmaxf(acc[st][fi][rg] + bias, 0.f) : 0.f;
                A2[s * A2P + f] = (short)f2bf(v);
            }
        }
    __syncthreads();

    // FC MFMA + epilogue (waves 0,1; wave = s-tile)
    if (wv < 2) {
        v4f a2[4];
#pragma unroll
        for (int nt = 0; nt < 4; ++nt) a2[nt] = (v4f){0.f, 0.f, 0.f, 0.f};
#pragma unroll
        for (int ks = 0; ks < 4; ++ks) {
            v8s af = ldsld8(&A2[(wv * 16 + col) * A2P + ks * 32 + q * 8]);
#pragma unroll
            for (int nt = 0; nt < 4; ++nt) {
                v8s bt = ldsld8(&B2[((ks * 4 + nt) << 9) + bofs]);
                a2[nt] = MFMA16(af, bt, a2[nt], 0, 0, 0);
            }
        }
        float fb0 = fcb[col], fb1 = fcb[16 + col], fb2 = fcb[32 + col];
        float fb3 = (col < 2) ? fcb[48 + col] : 0.f;
#pragma unroll
        for (int rg = 0; rg < 4; ++rg) {
            int s = s0 + wv * 16 + q * 4 + rg;
            float e0v = a2[0][rg] + fb0;
            float e1v = a2[1][rg] + fb1;
            float e2v = a2[2][rg] + fb2;
            float e3v = (col < 2) ? a2[3][rg] + fb3 : -1e30f;
            float m = fmaxf(fmaxf(e0v, e1v), fmaxf(e2v, e3v));
#pragma unroll
            for (int off = 1; off < 16; off <<= 1) m = fmaxf(m, __shfl_xor(m, off));
            int gidx = b * SS + s;
            if (col == 0) rmv[gidx] = m;
            int tg = tags[gidx];
            float* orow = expem + (size_t)gidx * TT;
            orow[col]      = __expf(e0v - m);
            orow[16 + col] = __expf(e1v - m);
            orow[32 + col] = __expf(e2v - m);
            if (col < 2) orow[48 + col] = __expf(e3v - m);
            if (tg == col)            emtag[gidx] = e0v;
            else if (tg == 16 + col)  emtag[gidx] = e1v;
            else if (tg == 32 + col)  emtag[gidx] = e2v;
            else if (col < 2 && tg == 48 + col) emtag[gidx] = e3v;
        }
    }
}

// ---------------------------------------------------------------------------
// RMxT product of two 64x64 LDS matrices (stride MP).  Verified in round 2
// (tree kernel passed absmax 0): SA in RM-form (SA[m][k]=Mat[m][k]), SB in
// T-form (SB[n][k]=Mat[k][n]); both read with the same fragment pattern.
// ---------------------------------------------------------------------------
__device__ inline void prodLDS(const short* SA, const short* SB, int col, int q,
                               v4f (&acc)[4][4]) {
    v8s a[4][2], bb[4][2];
#pragma unroll
    for (int jt = 0; jt < 4; ++jt)
#pragma unroll
        for (int kc = 0; kc < 2; ++kc)
            a[jt][kc] = ldsld8(&SA[(jt * 16 + col) * MP + kc * 32 + q * 8]);
#pragma unroll
    for (int nt = 0; nt < 4; ++nt)
#pragma unroll
        for (int kc = 0; kc < 2; ++kc)
            bb[nt][kc] = ldsld8(&SB[(nt * 16 + col) * MP + kc * 32 + q * 8]);
#pragma unroll
    for (int jt = 0; jt < 4; ++jt)
#pragma unroll
        for (int nt = 0; nt < 4; ++nt) {
            acc[jt][nt] = (v4f){0.f, 0.f, 0.f, 0.f};
            acc[jt][nt] = MFMA16(a[jt][0], bb[nt][0], acc[jt][nt], 0, 0, 0);
            acc[jt][nt] = MFMA16(a[jt][1], bb[nt][1], acc[jt][nt], 0, 0, 0);
        }
}

// ---------------------------------------------------------------------------
// Kernel B1: per-(batch,chunk) product of 16 step matrices.  CHANGE vs R0:
// the 15-step sequential product is split into TWO INDEPENDENT 8-step halves,
// one per wave (128 threads).  No cross-wave sync in the step loop -- each
// wave owns a private L double-buffer and uses a wave-local lgkmcnt drain
// (cross-lane visibility within one wave needs no s_barrier).  One barrier,
// then wave 0 multiplies the halves (RMxT prodLDS, verified in R2) and runs
// the R0-verbatim max-normalize epilogue.  Critical path 15 -> 8 steps + 1
// product; LDS 40 KB -> 4 blocks/CU x 2 waves = 8 waves/CU (2/SIMD).
// grid (NC, BB), 128 threads.
// ---------------------------------------------------------------------------
__global__ __launch_bounds__(128) void chunk_kernel(
    const float* __restrict__ expem, const unsigned short* __restrict__ AT,
    const unsigned short* __restrict__ Ab,
    unsigned short* __restrict__ R, float* __restrict__ lsR)
{
    __shared__ __align__(16) short L[4][64 * MP];   // 36864 B: 2 slots per wave
    __shared__ __align__(16) float emL[CH][64];     // 4096 B
    const int c = blockIdx.x, b = blockIdx.y;
    const int tid  = threadIdx.x;
    const int wv   = tid >> 6;
    const int lane = tid & 63;
    const int col = lane & 15, q = lane >> 4;
    const int t0 = c * CH + 1;
    const int nf = (c == NC - 1) ? (SS - 1 - (NC - 1) * CH) : CH;   // 15 or 16

    for (int idx = tid; idx < CH * 64; idx += 128) {
        int k = idx >> 6, m = idx & 63;
        float v = 0.f;
        if (m < TT && k < nf) v = expem[((size_t)(b * SS + t0 + k)) * TT + m];
        emL[k][m] = v;
    }

    v8s af[4][2];
#pragma unroll
    for (int jt = 0; jt < 4; ++jt)
#pragma unroll
        for (int kc = 0; kc < 2; ++kc)
            af[jt][kc] = *(const v8s*)(AT + (jt * 16 + col) * 64 + kc * 32 + q * 8);
    __syncthreads();                                 // emL visible to both waves

    // ---- wave-local half product: wave wv covers steps k0..k0+hn-1 ----
    const int k0 = wv * 8;
    const int hn = wv ? (nf - 8) : 8;                // 8 | 8 (nf=16) or 8 | 7
    short* Lp = &L[wv * 2][0];                       // slot s at Lp + s*64*MP

    {   // leaf M_{k0} = diag(em_{k0}) * A^T, T-form into slot 0
        const v8s* arow = (const v8s*)(Ab + lane * 64);
#pragma unroll
        for (int g = 0; g < 8; ++g) {
            v8s a = arow[g];
            float f[8];
#pragma unroll
            for (int e = 0; e < 8; ++e) f[e] = bf2f(a[e]) * emL[k0][g * 8 + e];
            uint4 o = make_uint4(pkbf2(f[0], f[1]), pkbf2(f[2], f[3]),
                                 pkbf2(f[4], f[5]), pkbf2(f[6], f[7]));
            *(uint4*)&Lp[lane * MP + g * 8] = o;
        }
    }

    int cur = 0;
    for (int j = 1; j < hn; ++j) {
        const int k = k0 + j;
        wavesync();                                  // prior lane-writes visible
        v8s bf[4][2];
#pragma unroll
        for (int nt = 0; nt < 4; ++nt)
#pragma unroll
            for (int kc = 0; kc < 2; ++kc)
                bf[nt][kc] = ldsld8(&Lp[cur * (64 * MP) +
                                        (nt * 16 + col) * MP + kc * 32 + q * 8]);
        v4f acc[4][4];
#pragma unroll
        for (int jt = 0; jt < 4; ++jt)
#pragma unroll
            for (int nt = 0; nt < 4; ++nt) {
                acc[jt][nt] = (v4f){0.f, 0.f, 0.f, 0.f};
                acc[jt][nt] = MFMA16(af[jt][0], bf[nt][0], acc[jt][nt], 0, 0, 0);
                acc[jt][nt] = MFMA16(af[jt][1], bf[nt][1], acc[jt][nt], 0, 0, 0);
            }
        short* Ld = &Lp[(cur ^ 1) * (64 * MP)];
        if (j < hn - 1) {                            // T-form, continue
#pragma unroll
            for (int jt = 0; jt < 4; ++jt) {
                const float4 em4 = *(const float4*)&emL[k][jt * 16 + q * 4];
#pragma unroll
                for (int nt = 0; nt < 4; ++nt) {
                    uint2 o = make_uint2(
                        pkbf2(acc[jt][nt][0] * em4.x, acc[jt][nt][1] * em4.y),
                        pkbf2(acc[jt][nt][2] * em4.z, acc[jt][nt][3] * em4.w));
                    *(uint2*)&Ld[(nt * 16 + col) * MP + jt * 16 + q * 4] = o;
                }
            }
            cur ^= 1;
        } else if (wv == 0) {                        // H0 final: T-form (B-op)
#pragma unroll
            for (int jt = 0; jt < 4; ++jt) {
                const float4 em4 = *(const float4*)&emL[k][jt * 16 + q * 4];
#pragma unroll
                for (int nt = 0; nt < 4; ++nt) {
                    uint2 o = make_uint2(
                        pkbf2(acc[jt][nt][0] * em4.x, acc[jt][nt][1] * em4.y),
                        pkbf2(acc[jt][nt][2] * em4.z, acc[jt][nt][3] * em4.w));
                    *(uint2*)&Ld[(nt * 16 + col) * MP + jt * 16 + q * 4] = o;
                }
            }
        } else {                                     // H1 final: RM-form (A-op)
#pragma unroll
            for (int jt = 0; jt < 4; ++jt) {
                const float4 em4 = *(const float4*)&emL[k][jt * 16 + q * 4];
#pragma unroll
                for (int nt = 0; nt < 4; ++nt) {
                    Ld[(jt * 16 + q * 4 + 0) * MP + nt * 16 + col] = (short)f2bf(acc[jt][nt][0] * em4.x);
                    Ld[(jt * 16 + q * 4 + 1) * MP + nt * 16 + col] = (short)f2bf(acc[jt][nt][1] * em4.y);
                    Ld[(jt * 16 + q * 4 + 2) * MP + nt * 16 + col] = (short)f2bf(acc[jt][nt][2] * em4.z);
                    Ld[(jt * 16 + q * 4 + 3) * MP + nt * 16 + col] = (short)f2bf(acc[jt][nt][3] * em4.w);
                }
            }
        }
    }
    __syncthreads();                                 // halves visible; wave1 done
    if (wv != 0) return;

    // ---- final: P = H1 * H0 (RM x T); max-normalize; write R, lsR ----
    // out slot of a half with hn steps = (hn-1)&1  (init slot 0, flips on
    // non-final multiplies): hn=8 -> 1, hn=7 -> 0.
    const short* H0 = &L[0][0] + 1 * (64 * MP);              // hn0=8 always
    const short* H1 = &L[2][0] + (((nf - 8) - 1) & 1) * (64 * MP);
    v4f acc[4][4];
    prodLDS(H1, H0, col, q, acc);
    float mx = 0.f;
#pragma unroll
    for (int jt = 0; jt < 4; ++jt)
#pragma unroll
        for (int nt = 0; nt < 4; ++nt)
#pragma unroll
            for (int r = 0; r < 4; ++r) mx = fmaxf(mx, acc[jt][nt][r]);
#pragma unroll
    for (int off = 1; off < 64; off <<= 1) mx = fmaxf(mx, __shfl_xor(mx, off));
    mx = fmaxf(mx, 1e-37f);
    float inv = 1.f / mx;
    unsigned short* Rc = R + ((size_t)(b * NC + c) << 12);
#pragma unroll
    for (int jt = 0; jt < 4; ++jt)
#pragma unroll
        for (int nt = 0; nt < 4; ++nt)
#pragma unroll
            for (int r = 0; r < 4; ++r)
                Rc[(jt * 16 + q * 4 + r) * 64 + nt * 16 + col] =
                    f2bf(acc[jt][nt][r] * inv);
    if (lane == 0) lsR[b * NC + c] = __logf(mx);
}

// ---------------------------------------------------------------------------
// Chain helpers: spill-free dot (named accumulators, static indexing only).
// ---------------------------------------------------------------------------
__device__ inline float chaindot(const v8s (&buf)[8], const float* pvec) {
    const float4* pv4 = (const float4*)__builtin_assume_aligned(pvec, 16);
    float a0 = 0.f, a1 = 0.f, a2 = 0.f, a3 = 0.f;   // 4 chains: dep 256->64 cy
#pragma unroll
    for (int g = 0; g < 8; ++g) {
        v8s v = buf[g];
        float4 pA = pv4[g * 2], pB = pv4[g * 2 + 1];
        float* aa = (g & 3) == 0 ? &a0 : (g & 3) == 1 ? &a1 : (g & 3) == 2 ? &a2 : &a3;
        float t = *aa;
        t = fmaf(bf2f(v[0]), pA.x, t);
        t = fmaf(bf2f(v[1]), pA.y, t);
        t = fmaf(bf2f(v[2]), pA.z, t);
        t = fmaf(bf2f(v[3]), pA.w, t);
        t = fmaf(bf2f(v[4]), pB.x, t);
        t = fmaf(bf2f(v[5]), pB.y, t);
        t = fmaf(bf2f(v[6]), pB.z, t);
        t = fmaf(bf2f(v[7]), pB.w, t);
        *aa = t;
    }
    return (a0 + a1) + (a2 + a3);
}

__device__ inline void chainfin(float acc2, float* pvec, int i, float& logacc) {
    float mx = acc2;
#pragma unroll
    for (int off = 1; off < 64; off <<= 1) mx = fmaxf(mx, __shfl_xor(mx, off));
    mx = fmaxf(mx, 1e-37f);
    logacc += __logf(mx);
    pvec[i] = acc2 * (1.f / mx);
}

// ---------------------------------------------------------------------------
// Kernel B2: chain + numerator + atomic finish.  (R4 verbatim)
// grid BB, 256 threads.
// ---------------------------------------------------------------------------
__global__ __launch_bounds__(256) void chain_kernel(
    const float* __restrict__ expem, const unsigned short* __restrict__ R,
    const float* __restrict__ lsR, const float* __restrict__ start,
    const float* __restrict__ endt,
    const float* __restrict__ emtag, const float* __restrict__ rmv,
    const int* __restrict__ tags, const float* __restrict__ tr,
    float* __restrict__ accum, unsigned* __restrict__ cnt,
    float* __restrict__ out)
{
    __shared__ __align__(16) float pvec[64];
    __shared__ float red[8];
    __shared__ float lzsh;
    const int b = blockIdx.x, tid = threadIdx.x;
    const int wv = tid >> 6, i = tid & 63;

    if (wv == 0) {
        pvec[i] = (i < TT) ? __expf(start[i]) * expem[((size_t)(b * SS)) * TT + i] : 0.f;
        float lsv = (i < NC) ? lsR[b * NC + i] : 0.f;   // hoist all 32 lsR reads
#pragma unroll
        for (int off = 1; off < 64; off <<= 1) lsv += __shfl_xor(lsv, off);

        const unsigned short* Rb = R + ((size_t)(b * NC) << 12);
        v8s bufA[8], bufB[8];                  // 64 VGPR register double-buffer
#pragma unroll
        for (int g = 0; g < 8; ++g)
            bufA[g] = *(const v8s*)(Rb + i * 64 + g * 8);
        float logacc = 0.f;
#pragma unroll 1
        for (int cc = 0; cc < NC; cc += 2) {
            const unsigned short* R1 = Rb + ((size_t)(cc + 1) << 12);
#pragma unroll
            for (int g = 0; g < 8; ++g)
                bufB[g] = *(const v8s*)(R1 + i * 64 + g * 8);
            float acc2 = chaindot(bufA, pvec);
            chainfin(acc2, pvec, i, logacc);
            if (cc + 2 < NC) {
                const unsigned short* R2 = Rb + ((size_t)(cc + 2) << 12);
#pragma unroll
                for (int g = 0; g < 8; ++g)
                    bufA[g] = *(const v8s*)(R2 + i * 64 + g * 8);
            }
            acc2 = chaindot(bufB, pvec);
            chainfin(acc2, pvec, i, logacc);
        }
        float sv = (i < TT) ? pvec[i] * __expf(endt[i]) : 0.f;
#pragma unroll
        for (int off = 1; off < 64; off <<= 1) sv += __shfl_xor(sv, off);
        if (i == 0) lzsh = logacc + lsv + __logf(sv);
    } else {
        float accN = 0.f, accR = 0.f;
        for (int s = tid - 64; s < SS; s += 192) {
            int gi = b * SS + s;
            accN += emtag[gi];
            accR += rmv[gi];
            int tg = tags[gi];
            if (s < SS - 1) accN += tr[tg * TT + tags[gi + 1]];
        }
#pragma unroll
        for (int off = 1; off < 64; off <<= 1) {
            accN += __shfl_xor(accN, off);
            accR += __shfl_xor(accR, off);
        }
        if (i == 0) { red[wv] = accN; red[4 + wv] = accR; }
    }
    __syncthreads();
    if (tid == 0) {
        float tn  = red[1] + red[2] + red[3];
        float trm = red[5] + red[6] + red[7];
        float num = tn + start[tags[b * SS]] + endt[tags[b * SS + SS - 1]];
        float nll = trm + lzsh - num;
        atomicAdd(accum, nll);
        __threadfence();
        unsigned old = atomicAdd(cnt, 1u);
        if (old == BB - 1) out[0] = atomicAdd(accum, 0.f);
    }
}

extern "C" void kernel_launch(void* const* d_in, const int* in_sizes, int n_in,
                              void* d_out, int out_size, void* d_ws, size_t ws_size,
                              hipStream_t stream)
{
    const int*   x    = (const int*)d_in[0];
    const int*   tags = (const int*)d_in[1];
    const float* emb  = (const float*)d_in[2];
    const float* cw   = (const float*)d_in[3];
    const float* cb   = (const float*)d_in[4];
    const float* fcw  = (const float*)d_in[5];
    const float* fcb  = (const float*)d_in[6];
    const float* st   = (const float*)d_in[7];
    const float* en   = (const float*)d_in[8];
    const float* tr   = (const float*)d_in[9];

    unsigned short* wB2   = (unsigned short*)d_ws;            // 122880 sh
    unsigned short* fcwT2 = wB2 + NCH * CKS * 8 * 512;        // 8192 sh
    unsigned short* ATm   = fcwT2 + 16 * 512;                 // 4096 sh
    unsigned short* Abm   = ATm + 4096;                       // 4096 sh
    unsigned short* Rm    = Abm + 4096;                       // BB*NC*4096 sh = 8 MB
    float* fbase   = (float*)(Rm + (size_t)BB * NC * 4096);
    float* expem   = fbase;                                   // 819200
    float* rmv     = expem + (size_t)BB * SS * TT;            // 16384
    float* emtag   = rmv + BB * SS;                           // 16384
    float* lsR     = emtag + BB * SS;                         // 1024
    float* accum   = lsR + BB * NC;                           // 1
    unsigned* cnt  = (unsigned*)(accum + 1);                  // 1

    prep_kernel<<<dim3(64), 256, 0, stream>>>(tr, cw, fcw, wB2, fcwT2, ATm, Abm,
                                              accum, cnt);
    emis_kernel<<<dim3(16, BB), 256, 0, stream>>>(x, emb, wB2, cb, fcwT2, fcb,
                                                  tags, expem, rmv, emtag);
    chunk_kernel<<<dim3(NC, BB), 128, 0, stream>>>(expem, ATm, Abm, Rm, lsR);
    chain_kernel<<<dim3(BB), 256, 0, stream>>>(expem, Rm, lsR, st, en,
                                               emtag, rmv, tags, tr,
                                               accum, cnt, (float*)d_out);
}